// Round 5
// baseline (284.962 us; speedup 1.0000x reference)
//
#include <hip/hip_runtime.h>
#include <hip/hip_bf16.h>

typedef unsigned short u16;
typedef unsigned int   u32;

#define NB 32
#define CC 64
#define TT 300
#define VV 25
#define OO 128
#define TO 150
#define KT 9
#define MM 7500          // T*V rows per n (gcn GEMM)
#define MT 59            // ceil(7500/128)
#define M2 3750          // T2*V rows per n (tcn/res GEMMs)

typedef short s8v  __attribute__((ext_vector_type(8)));
typedef float f4v  __attribute__((ext_vector_type(4)));
typedef u16  h4v  __attribute__((ext_vector_type(4)));
typedef u16  h8v  __attribute__((ext_vector_type(8)));

__device__ __forceinline__ float b2f(u16 u){
  union { u32 i; float f; } c; c.i = ((u32)u) << 16; return c.f;
}
__device__ __forceinline__ u16 f2b(float f){
  __hip_bfloat16 h = __float2bfloat16(f);
  return *reinterpret_cast<u16*>(&h);
}
__device__ __forceinline__ void async16(const void* g, void* l){
  __builtin_amdgcn_global_load_lds((const __attribute__((address_space(1))) u32*)g,
                                   (__attribute__((address_space(3))) u32*)l, 16, 0, 0);
}

// ---------------- prep: A_sum + zero-page + tcn_w repack + gcn_w/res_w bf16 ----------------
// Wq2 layout (v4): step s = k*4 + iq (s<36), Wq2[s][o][j] = tcn_w[o][iq*32+j][k], j<32.
__global__ __launch_bounds__(256) void k_prep(const float* __restrict__ Ap, const float* __restrict__ ei,
                                              const float* __restrict__ tw, const float* __restrict__ gw,
                                              const float* __restrict__ rw,
                                              float* __restrict__ Asum, float* __restrict__ zbuf,
                                              u16* __restrict__ Wq2, u16* __restrict__ gwb,
                                              u16* __restrict__ rwb){
  int idx = blockIdx.x * 256 + threadIdx.x;
  if (idx < VV*VV){
    float s = 0.f;
    for (int p = 0; p < 3; ++p) s += ei[p] * Ap[p*VV*VV + idx];
    Asum[idx] = s;
  }
  if (idx >= 640 && idx < 768) zbuf[idx - 640] = 0.f;   // 512 B zero page
  int w = idx - 1024;
  if (w >= 0 && w < 36*OO*32){
    int s  = w >> 12;          // 128*32 = 4096 per step
    int r  = w & 4095;
    int o  = r >> 5;
    int j  = r & 31;
    int k  = s >> 2;
    int iq = s & 3;
    Wq2[w] = f2b(tw[o*(OO*KT) + (iq*32 + j)*KT + k]);   // Wq2[s][o][j] = tcn_w[o][iq*32+j][k]
  }
  int w2 = idx - 148480;
  if (w2 >= 0 && w2 < OO*CC) gwb[w2] = f2b(gw[w2]);   // gwb[o][c]
  int w3 = idx - 156672;
  if (w3 >= 0 && w3 < OO*CC) rwb[w3] = f2b(rw[w3]);   // rwb[o][c]
}

// ---------------- gcn: register-direct MFMA agg + MFMA GEMM: M=(t*25+v), N=128 o, K=64 c ----------------
// xg layout: [n][m=t*25+v][o].  LDS = 32 KB; no x staging buffer.
__global__ __launch_bounds__(256, 4) void k_gcnm(const float* __restrict__ x, const float* __restrict__ Asum,
                                                 const u16* __restrict__ gwb, const float* __restrict__ gb,
                                                 u16* __restrict__ xg){
  __shared__ __align__(16) u16 A_lds[128*64];   // 16 KB, XOR-swizzled granules
  __shared__ __align__(16) u16 B_lds[128*64];   // 16 KB, XOR-swizzled granules
  int bx = blockIdx.x;
  int n  = bx / MT;
  int m0 = (bx % MT) * 128;
  int t0 = m0 / VV, r0 = m0 % VV;
  int tid = threadIdx.x;
  int lane = tid & 63, wv = tid >> 6;
  int wm = (wv & 1) * 64, wo = (wv >> 1) * 64;
  int lr = lane & 15, lq = lane >> 4;

  // ---- stage B (gwb, 16 KB) with plain coalesced loads + swizzled ds_write ----
  {
    const u32* g32 = (const u32*)gwb;
    u32* b32 = (u32*)B_lds;
    for (int s = tid; s < 4096; s += 256){
      int row = s >> 5, col = s & 31;
      int g = col >> 2, c2 = col & 3;
      b32[row*32 + ((g ^ (row & 7))*4 + c2)] = g32[s];
    }
  }

  // ---- A_sum^T B-fragments in registers: bfw[wt], lane holds B[w=lr+16wt][v=lq*8+j] ----
  s8v bfw[2];
  #pragma unroll
  for (int wt = 0; wt < 2; ++wt){
    u16 tmp[8];
    int w = lr + 16*wt;
    #pragma unroll
    for (int j = 0; j < 8; ++j){
      int v = lq*8 + j;
      tmp[j] = (w < VV && v < VV) ? f2b(Asum[v*VV + w]) : (u16)0;
    }
    bfw[wt] = *(s8v*)tmp;
  }

  // ---- agg via MFMA with register-direct A: 28 tasks (7 it x 4 ct) over 4 waves ----
  #pragma unroll
  for (int tt = 0; tt < 7; ++tt){
    int tau = tt*4 + wv;
    int it = tau >> 2, ct = tau & 3;
    int t  = t0 + it;
    int c  = ct*16 + lr;
    const float* xp = x + ((size_t)(n*CC + c)*TT + t)*VV + lq*8;
    float4 xa = make_float4(0.f,0.f,0.f,0.f), xb = xa;
    float x24 = 0.f;
    if (t < TT){
      if (lq < 3){
        xa = *(const float4*)xp;
        xb = *(const float4*)(xp + 4);
      } else {
        x24 = xp[0];
      }
    }
    u16 pk[8];
    if (lq < 3){
      pk[0]=f2b(xa.x); pk[1]=f2b(xa.y); pk[2]=f2b(xa.z); pk[3]=f2b(xa.w);
      pk[4]=f2b(xb.x); pk[5]=f2b(xb.y); pk[6]=f2b(xb.z); pk[7]=f2b(xb.w);
    } else {
      pk[0]=f2b(x24); pk[1]=0; pk[2]=0; pk[3]=0; pk[4]=0; pk[5]=0; pk[6]=0; pk[7]=0;
    }
    s8v af = *(s8v*)pk;
    f4v d0 = (f4v)(0.f), d1 = (f4v)(0.f);
    d0 = __builtin_amdgcn_mfma_f32_16x16x32_bf16(af, bfw[0], d0, 0, 0, 0);
    d1 = __builtin_amdgcn_mfma_f32_16x16x32_bf16(af, bfw[1], d1, 0, 0, 0);
    int cb = ct*16 + lq*4;
    int g  = cb >> 3, co = cb & 7;
    int ml0 = it*VV + lr - r0;                    // w = lr
    if (ml0 >= 0 && ml0 < 128){
      u16 q[4];
      #pragma unroll
      for (int rg = 0; rg < 4; ++rg) q[rg] = f2b(d0[rg]);
      *(h4v*)&A_lds[ml0*64 + ((g ^ (ml0 & 7))*8) + co] = *(h4v*)q;
    }
    int w1 = lr + 16;
    int ml1 = it*VV + w1 - r0;
    if (w1 < VV && ml1 >= 0 && ml1 < 128){
      u16 q[4];
      #pragma unroll
      for (int rg = 0; rg < 4; ++rg) q[rg] = f2b(d1[rg]);
      *(h4v*)&A_lds[ml1*64 + ((g ^ (ml1 & 7))*8) + co] = *(h4v*)q;
    }
  }
  __syncthreads();

  // ---- main GEMM: 64m x 64o per wave, K=64 (2 substeps) ----
  f4v acc[4][4];
  #pragma unroll
  for (int mi = 0; mi < 4; ++mi)
    #pragma unroll
    for (int ni = 0; ni < 4; ++ni) acc[mi][ni] = (f4v)(0.f);
  #pragma unroll
  for (int ks = 0; ks < 2; ++ks){
    int p = ((ks*4 + lq) ^ (lane & 7)) * 8;
    s8v af[4], bf[4];
    #pragma unroll
    for (int mi = 0; mi < 4; ++mi)
      af[mi] = *(const s8v*)&A_lds[(wm + mi*16 + lr)*64 + p];
    #pragma unroll
    for (int ni = 0; ni < 4; ++ni)
      bf[ni] = *(const s8v*)&B_lds[(wo + ni*16 + lr)*64 + p];
    #pragma unroll
    for (int mi = 0; mi < 4; ++mi)
      #pragma unroll
      for (int ni = 0; ni < 4; ++ni)
        acc[mi][ni] = __builtin_amdgcn_mfma_f32_16x16x32_bf16(af[mi], bf[ni], acc[mi][ni], 0, 0, 0);
  }

  float bias[4];
  #pragma unroll
  for (int ni = 0; ni < 4; ++ni) bias[ni] = gb[wo + ni*16 + lr];
  #pragma unroll
  for (int mi = 0; mi < 4; ++mi){
    int mr = m0 + wm + mi*16 + lq*4;
    #pragma unroll
    for (int ni = 0; ni < 4; ++ni){
      int o = wo + ni*16 + lr;
      #pragma unroll
      for (int rg = 0; rg < 4; ++rg){
        int m = mr + rg;
        if (m < MM)
          xg[((size_t)n*MM + m)*OO + o] = f2b(acc[mi][ni][rg] + bias[ni]);
      }
    }
  }
}

// ---------------- tcn as MFMA implicit GEMM + fused BN partial stats ----------------
// v5: K-step 32, 512 thr, 4 blocks/CU (36 KB LDS), counted vmcnt(2) pipeline.
// Fixes vs v4 (R4 counters: 6.6M bank conflicts, FETCH 157 MB):
//  (a) granule swizzle g = d ^ ((row>>1)&3): bank class = 4(lr&1) + (lq^((lr>>1)&3))
//      -> 2 lanes/class per 16-lane phase = conflict-free (was 8-way).
//  (b) chunked XCD swizzle: lg = (bx&7)*120 + bx>>3 -> each XCD owns 120 contiguous
//      logical tiles (4 n's) so overlapping conv t-windows / xt lines stay in one L2.
__global__ __launch_bounds__(512, 8) void k_tcnm(const u16* __restrict__ xg, const u16* __restrict__ Wq2,
                                                 const float* __restrict__ tb, const u16* __restrict__ zbuf,
                                                 u16* __restrict__ xt, float* __restrict__ psum,
                                                 float* __restrict__ psq){
  __shared__ __align__(16) u16 A_lds[2][128*32];   // 2 x 8 KB
  __shared__ __align__(16) u16 B_lds[2][128*32];   // 2 x 8 KB
  __shared__ float sredS[8][64];
  __shared__ float sredQ[8][64];
  int bx = blockIdx.x;
  int lg = ((bx & 7) * 120) + (bx >> 3);   // bijective: 960 = 8 * 120
  int n  = lg / 30;
  int m0 = (lg % 30) * 128;
  int tid = threadIdx.x;
  int lane = tid & 63, wv = tid >> 6;
  int wm = (wv >> 1) * 32, wo = (wv & 1) * 64;   // 8 waves: 4 m-strips x 2 o-halves
  int lr = lane & 15, lq = lane >> 4;

  int rlow = tid >> 2;                 // 0..127: row within 128-row tile
  int gs   = ((tid & 3) ^ ((tid >> 3) & 3)) * 8;   // data granule d = g ^ ((row>>1)&3)
  int tid16 = tid * 16;
  int m = m0 + rlow;
  bool vmv = (m < M2);
  int t2v = m / VV, vrv = m - t2v*VV;
  int tb2 = 2*t2v - 4;
  size_t basen = (size_t)n*MM*OO + gs;

  f4v acc[2][4];
  #pragma unroll
  for (int mi = 0; mi < 2; ++mi)
    #pragma unroll
    for (int ni = 0; ni < 4; ++ni) acc[mi][ni] = (f4v)(0.f);

  // 2 global_load_lds per thread per step (1 A granule + 1 B granule)
  auto stage = [&](int s, int b){
    int k  = s >> 2;
    int iq = s & 3;
    int t  = tb2 + k;
    const u16* ga = (vmv && t >= 0 && t < TT)
                    ? xg + basen + (size_t)(t*VV + vrv)*OO + iq*32
                    : zbuf;
    async16(ga, (char*)(&A_lds[b][0]) + tid16);
    async16(Wq2 + (size_t)s*4096 + rlow*32 + gs, (char*)(&B_lds[b][0]) + tid16);
  };

  int pA = (lq ^ ((lr >> 1) & 3)) * 8;   // swizzled granule slot for ds_read

  stage(0, 0);                         // prologue: tile 0 in flight (2 loads/thread)
  for (int s = 0; s < 36; ++s){
    int cur = s & 1;
    if (s < 35){
      stage(s + 1, cur ^ 1);           // 4 outstanding per thread
      asm volatile("s_waitcnt vmcnt(2)" ::: "memory");   // cur's 2 landed; next 2 in flight
    } else {
      asm volatile("s_waitcnt vmcnt(0)" ::: "memory");   // last tile: drain
    }
    __builtin_amdgcn_s_barrier();      // all waves' cur-tile loads visible
    asm volatile("" ::: "memory");     // fence: keep ds_reads below the barrier

    const u16* Ac = &A_lds[cur][0];
    const u16* Bc = &B_lds[cur][0];
    s8v af[2], bf[4];
    #pragma unroll
    for (int mi = 0; mi < 2; ++mi)
      af[mi] = *(const s8v*)&Ac[(wm + mi*16 + lr)*32 + pA];
    #pragma unroll
    for (int ni = 0; ni < 4; ++ni)
      bf[ni] = *(const s8v*)&Bc[(wo + ni*16 + lr)*32 + pA];
    #pragma unroll
    for (int mi = 0; mi < 2; ++mi)
      #pragma unroll
      for (int ni = 0; ni < 4; ++ni)
        acc[mi][ni] = __builtin_amdgcn_mfma_f32_16x16x32_bf16(af[mi], bf[ni], acc[mi][ni], 0, 0, 0);

    asm volatile("s_waitcnt lgkmcnt(0)" ::: "memory");   // reads complete before crossing
    __builtin_amdgcn_s_barrier();      // all waves done reading cur -> safe to overwrite
    asm volatile("" ::: "memory");
  }

  float bias[4];
  #pragma unroll
  for (int ni = 0; ni < 4; ++ni) bias[ni] = tb[wo + ni*16 + lr];
  float sni[4] = {0.f,0.f,0.f,0.f}, qni[4] = {0.f,0.f,0.f,0.f};
  #pragma unroll
  for (int mi = 0; mi < 2; ++mi){
    int mr = m0 + wm + mi*16 + lq*4;
    #pragma unroll
    for (int ni = 0; ni < 4; ++ni){
      int o = wo + ni*16 + lr;
      #pragma unroll
      for (int rg = 0; rg < 4; ++rg){
        int mm = mr + rg;
        if (mm < M2){
          float val = acc[mi][ni][rg] + bias[ni];
          xt[((size_t)n*M2 + mm)*OO + o] = f2b(val);
          sni[ni] += val;
          qni[ni] += val*val;
        }
      }
    }
  }
  // cross-lq reduce (lanes differ by 16/32), then cross-wave combine via LDS
  #pragma unroll
  for (int ni = 0; ni < 4; ++ni){
    float s = sni[ni], q = qni[ni];
    s += __shfl_xor(s, 16); s += __shfl_xor(s, 32);
    q += __shfl_xor(q, 16); q += __shfl_xor(q, 32);
    if (lane < 16){
      sredS[wv][ni*16 + lane] = s;
      sredQ[wv][ni*16 + lane] = q;
    }
  }
  __syncthreads();
  // waves with (wv&1) == (o>>6) cover output column o; 4 such waves each
  if (tid < 128){
    int o = tid, h = o >> 6, lo = o & 63;
    psum[(size_t)lg*128 + o] = (sredS[h][lo] + sredS[h+2][lo]) + (sredS[h+4][lo] + sredS[h+6][lo]);
  } else if (tid < 256){
    int o = tid - 128, h = o >> 6, lo = o & 63;
    psq [(size_t)lg*128 + o] = (sredQ[h][lo] + sredQ[h+2][lo]) + (sredQ[h+4][lo] + sredQ[h+6][lo]);
  }
}

// ---------------- BN stats finalize, stage a: 60 blocks reduce 16 partial rows each ----------------
__global__ __launch_bounds__(256) void k_stats2a(const float* __restrict__ psum, const float* __restrict__ psq,
                                                 float* __restrict__ ps2, float* __restrict__ pq2){
  __shared__ float bufS[256], bufQ[256];
  int tid = threadIdx.x, b = blockIdx.x;
  int o = tid & 127, h = tid >> 7;
  float s = 0.f, q = 0.f;
  for (int r = b*16 + h; r < b*16 + 16; r += 2){
    s += psum[(size_t)r*128 + o];
    q += psq [(size_t)r*128 + o];
  }
  bufS[tid] = s; bufQ[tid] = q;
  __syncthreads();
  if (tid < 128){
    ps2[(size_t)b*128 + o] = bufS[tid] + bufS[tid + 128];
    pq2[(size_t)b*128 + o] = bufQ[tid] + bufQ[tid + 128];
  }
}

// ---------------- BN stats finalize, stage b: reduce 60 level-2 rows ----------------
__global__ __launch_bounds__(256) void k_stats2b(const float* __restrict__ ps2, const float* __restrict__ pq2,
                                                 const float* __restrict__ gamma, const float* __restrict__ beta,
                                                 float* __restrict__ stats){
  __shared__ float bufS[256], bufQ[256];
  int tid = threadIdx.x;
  int o = tid & 127, h = tid >> 7;
  float s = 0.f, q = 0.f;
  for (int b = h; b < 60; b += 2){
    s += ps2[(size_t)b*128 + o];
    q += pq2[(size_t)b*128 + o];
  }
  bufS[tid] = s; bufQ[tid] = q;
  __syncthreads();
  if (tid < 128){
    s = bufS[tid] + bufS[tid + 128];
    q = bufQ[tid] + bufQ[tid + 128];
    const float inv = 1.f / 120000.f;
    float mean = s * inv;
    float var  = q * inv - mean*mean;
    float sc = gamma[o] * rsqrtf(var + 1e-5f);
    stats[o]       = sc;
    stats[128 + o] = beta[o] - mean * sc;
  }
}

// ---------------- res as MFMA implicit GEMM + BN + relu: M=(t2*25+v), N=128 o, K=64 c ----------------
// out[n][o][m] with m = t2*25+v  (== reference (N,O,T2,V))
// v4: coalesced output via LDS transpose (store loop covers all 64 rows: 16 iter x 4 rows).
__global__ __launch_bounds__(256, 4) void k_resm(const float* __restrict__ x, const u16* __restrict__ rwb,
                                                 const float* __restrict__ rb, const u16* __restrict__ xt,
                                                 const float* __restrict__ stats, float* __restrict__ out){
  __shared__ __align__(16) char smem[64*130*4];   // 33280 B: staging (32 KB) then transpose buf
  u16* A_lds = (u16*)smem;                        // [128*64]
  u16* B_lds = A_lds + 128*64;                    // [128*64]
  float* tbuf = (float*)smem;                     // [64][130] f32, aliases A/B after GEMM
  int bx = blockIdx.x;
  int n  = bx / 30;
  int m0 = (bx % 30) * 128;
  int t20 = m0 / VV, r0 = m0 % VV;
  int tid = threadIdx.x;
  int lane = tid & 63, wv = tid >> 6;
  int wm = (wv & 1) * 64, wo = (wv >> 1) * 64;
  int lr = lane & 15, lq = lane >> 4;

  {
    const u32* g32 = (const u32*)rwb;
    u32* b32 = (u32*)B_lds;
    for (int s = tid; s < 4096; s += 256){
      int row = s >> 5, col = s & 31;
      int g = col >> 2, c2 = col & 3;
      b32[row*32 + ((g ^ (row & 7))*4 + c2)] = g32[s];
    }
  }

  // stage A: tasks (cg, t2i, v): 8 c's packed into one ds_write_b128
  for (int task = tid; task < 8*7*VV; task += 256){
    int cg  = task / (7*VV);
    int rem = task - cg*(7*VV);
    int t2i = rem / VV, v = rem - t2i*VV;
    int t2 = t20 + t2i;
    int ml = t2i*VV + v - r0;
    if (ml >= 0 && ml < 128){
      u16 pk[8];
      if (t2 < TO){
        const float* xp = x + ((size_t)(n*CC + cg*8)*TT + 2*t2)*VV + v;
        #pragma unroll
        for (int cc = 0; cc < 8; ++cc) pk[cc] = f2b(xp[(size_t)cc*(TT*VV)]);
      } else {
        #pragma unroll
        for (int cc = 0; cc < 8; ++cc) pk[cc] = 0;
      }
      *(h8v*)&A_lds[ml*64 + ((cg ^ (ml & 7))*8)] = *(h8v*)pk;
    }
  }
  __syncthreads();

  f4v acc[4][4];
  #pragma unroll
  for (int mi = 0; mi < 4; ++mi)
    #pragma unroll
    for (int ni = 0; ni < 4; ++ni) acc[mi][ni] = (f4v)(0.f);
  #pragma unroll
  for (int ks = 0; ks < 2; ++ks){
    int p = ((ks*4 + lq) ^ (lane & 7)) * 8;
    s8v af[4], bf[4];
    #pragma unroll
    for (int mi = 0; mi < 4; ++mi)
      af[mi] = *(const s8v*)&A_lds[(wm + mi*16 + lr)*64 + p];
    #pragma unroll
    for (int ni = 0; ni < 4; ++ni)
      bf[ni] = *(const s8v*)&B_lds[(wo + ni*16 + lr)*64 + p];
    #pragma unroll
    for (int mi = 0; mi < 4; ++mi)
      #pragma unroll
      for (int ni = 0; ni < 4; ++ni)
        acc[mi][ni] = __builtin_amdgcn_mfma_f32_16x16x32_bf16(af[mi], bf[ni], acc[mi][ni], 0, 0, 0);
  }

  float sc[4], sb[4], rr[4];
  #pragma unroll
  for (int ni = 0; ni < 4; ++ni){
    int o = wo + ni*16 + lr;
    sc[ni] = stats[o]; sb[ni] = stats[128 + o]; rr[ni] = rb[o];
  }

  // ---- pass p: waves with wo==64p compute+deposit their o-half into tbuf; all store ----
  #pragma unroll
  for (int pass = 0; pass < 2; ++pass){
    __syncthreads();   // pass0: GEMM ds_reads done (smem reuse); pass1: prev stores done
    if ((wv >> 1) == pass){
      #pragma unroll
      for (int mi = 0; mi < 4; ++mi){
        int mb   = m0 + wm + mi*16 + lq*4;
        int mloc = wm + mi*16 + lq*4;
        #pragma unroll
        for (int ni = 0; ni < 4; ++ni){
          int o    = wo + ni*16 + lr;
          int oloc = ni*16 + lr;
          size_t xb = ((size_t)n*M2 + mb)*OO + o;
          float v2[4];
          #pragma unroll
          for (int rg = 0; rg < 4; ++rg){
            float val = 0.f;
            if (mb + rg < M2)
              val = fmaxf(sc[ni]*b2f(xt[xb + (size_t)rg*OO]) + sb[ni] + acc[mi][ni][rg] + rr[ni], 0.f);
            v2[rg] = val;
          }
          *(float2*)&tbuf[oloc*130 + mloc]     = make_float2(v2[0], v2[1]);
          *(float2*)&tbuf[oloc*130 + mloc + 2] = make_float2(v2[2], v2[3]);
        }
      }
    }
    __syncthreads();
    // cooperative coalesced store: 64 rows x 128 f32, float2 per lane, 4 rows/iter x 16
    #pragma unroll
    for (int it = 0; it < 16; ++it){
      int row = it*4 + (tid >> 6);        // 4 rows/iter, 64 lanes/row
      int c2  = (tid & 63) * 2;
      int o   = pass*64 + row;
      int mg  = m0 + c2;
      size_t ob = ((size_t)(n*OO + o))*M2 + mg;
      float2 vv = *(float2*)&tbuf[row*130 + c2];
      if (mg + 1 < M2)      *(float2*)&out[ob] = vv;
      else if (mg < M2)     out[ob] = vv.x;
    }
  }
}

extern "C" void kernel_launch(void* const* d_in, const int* in_sizes, int n_in,
                              void* d_out, int out_size, void* d_ws, size_t ws_size,
                              hipStream_t stream) {
  const float* x     = (const float*)d_in[0];
  const float* Ap    = (const float*)d_in[1];
  const float* ei    = (const float*)d_in[2];
  const float* gw    = (const float*)d_in[3];
  const float* gb    = (const float*)d_in[4];
  const float* tw    = (const float*)d_in[5];
  const float* tb    = (const float*)d_in[6];
  const float* gamma = (const float*)d_in[7];
  const float* beta  = (const float*)d_in[8];
  const float* rw    = (const float*)d_in[9];
  const float* rb    = (const float*)d_in[10];
  float* out = (float*)d_out;

  char* ws = (char*)d_ws;
  float* Asum  = (float*)ws;                      // 2500 B
  float* zbuf  = (float*)(ws + 2560);             // 512 B zero page
  u16*   Wq2   = (u16*)(ws + 4096);               // 294912 B -> 299008
  u16*   gwb   = (u16*)(ws + 299008);             // 16384 B  -> 315392
  u16*   rwb   = (u16*)(ws + 315392);             // 16384 B  -> 331776
  float* stats = (float*)(ws + 331776);           // 1024 B   -> 332800
  float* psum  = (float*)(ws + 333824);           // 491520 B -> 825344
  float* psq   = (float*)(ws + 825344);           // 491520 B -> 1316864
  float* ps2   = (float*)(ws + 1316864);          // 30720 B  -> 1347584
  float* pq2   = (float*)(ws + 1347584);          // 30720 B  -> 1378304
  u16*   xg    = (u16*)(ws + (2u<<20));           // 61,440,000 B [n][m=t*25+v][o] bf16
  u16*   xt    = (u16*)(ws + 63537152);           // 28,800,000 B [n][m=t2*25+v][o] bf16 (~92.3 MB total)

  k_prep   <<<dim3(644),    dim3(256), 0, stream>>>(Ap, ei, tw, gw, rw, Asum, zbuf, Wq2, gwb, rwb);
  k_gcnm   <<<dim3(NB*MT),  dim3(256), 0, stream>>>(x, Asum, gwb, gb, xg);
  k_tcnm   <<<dim3(NB*30),  dim3(512), 0, stream>>>(xg, Wq2, tb, (const u16*)zbuf, xt, psum, psq);
  k_stats2a<<<dim3(60),     dim3(256), 0, stream>>>(psum, psq, ps2, pq2);
  k_stats2b<<<dim3(1),      dim3(256), 0, stream>>>(ps2, pq2, gamma, beta, stats);
  k_resm   <<<dim3(NB*30),  dim3(256), 0, stream>>>(x, rwb, rb, xt, stats, out);
}

// Round 6
// 269.658 us; speedup vs baseline: 1.0568x; 1.0568x over previous
//
#include <hip/hip_runtime.h>
#include <hip/hip_bf16.h>

typedef unsigned short u16;
typedef unsigned int   u32;

#define NB 32
#define CC 64
#define TT 300
#define VV 25
#define OO 128
#define TO 150
#define KT 9
#define MM 7500          // T*V rows per n (gcn GEMM)
#define MT 59            // ceil(7500/128)
#define M2 3750          // T2*V rows per n (tcn/res GEMMs)

typedef short s8v  __attribute__((ext_vector_type(8)));
typedef float f4v  __attribute__((ext_vector_type(4)));
typedef u16  h4v  __attribute__((ext_vector_type(4)));
typedef u16  h8v  __attribute__((ext_vector_type(8)));

__device__ __forceinline__ float b2f(u16 u){
  union { u32 i; float f; } c; c.i = ((u32)u) << 16; return c.f;
}
__device__ __forceinline__ u16 f2b(float f){
  __hip_bfloat16 h = __float2bfloat16(f);
  return *reinterpret_cast<u16*>(&h);
}
__device__ __forceinline__ void async16(const void* g, void* l){
  __builtin_amdgcn_global_load_lds((const __attribute__((address_space(1))) u32*)g,
                                   (__attribute__((address_space(3))) u32*)l, 16, 0, 0);
}

// ---------------- prep: A_sum + zero-page + tcn_w repack + gcn_w/res_w bf16 ----------------
// Wq2 layout (K-64): kc = k*2 + half (kc<18), Wq2[kc][o][j] = tcn_w[o][(kc&1)*64+j][k], j<64.
__global__ __launch_bounds__(256) void k_prep(const float* __restrict__ Ap, const float* __restrict__ ei,
                                              const float* __restrict__ tw, const float* __restrict__ gw,
                                              const float* __restrict__ rw,
                                              float* __restrict__ Asum, float* __restrict__ zbuf,
                                              u16* __restrict__ Wq2, u16* __restrict__ gwb,
                                              u16* __restrict__ rwb){
  int idx = blockIdx.x * 256 + threadIdx.x;
  if (idx < VV*VV){
    float s = 0.f;
    for (int p = 0; p < 3; ++p) s += ei[p] * Ap[p*VV*VV + idx];
    Asum[idx] = s;
  }
  if (idx >= 640 && idx < 768) zbuf[idx - 640] = 0.f;   // 512 B zero page
  int w = idx - 1024;
  if (w >= 0 && w < 18*OO*64){
    int kc = w >> 13;
    int r  = w & 8191;
    int o  = r >> 6;
    int j  = r & 63;
    int k  = kc >> 1;
    int i  = (kc & 1)*64 + j;
    Wq2[w] = f2b(tw[o*(OO*KT) + i*KT + k]);   // Wq2[kc][o][j] = tcn_w[o][i][k]
  }
  int w2 = idx - 148480;
  if (w2 >= 0 && w2 < OO*CC) gwb[w2] = f2b(gw[w2]);   // gwb[o][c]
  int w3 = idx - 156672;
  if (w3 >= 0 && w3 < OO*CC) rwb[w3] = f2b(rw[w3]);   // rwb[o][c]
}

// ---------------- gcn: register-direct MFMA agg + MFMA GEMM: M=(t*25+v), N=128 o, K=64 c ----------------
// xg layout: [n][m=t*25+v][o].  LDS = 32 KB; no x staging buffer.
__global__ __launch_bounds__(256, 4) void k_gcnm(const float* __restrict__ x, const float* __restrict__ Asum,
                                                 const u16* __restrict__ gwb, const float* __restrict__ gb,
                                                 u16* __restrict__ xg){
  __shared__ __align__(16) u16 A_lds[128*64];   // 16 KB, XOR-swizzled granules
  __shared__ __align__(16) u16 B_lds[128*64];   // 16 KB, XOR-swizzled granules
  int bx = blockIdx.x;
  int n  = bx / MT;
  int m0 = (bx % MT) * 128;
  int t0 = m0 / VV, r0 = m0 % VV;
  int tid = threadIdx.x;
  int lane = tid & 63, wv = tid >> 6;
  int wm = (wv & 1) * 64, wo = (wv >> 1) * 64;
  int lr = lane & 15, lq = lane >> 4;

  // ---- stage B (gwb, 16 KB) with plain coalesced loads + swizzled ds_write ----
  {
    const u32* g32 = (const u32*)gwb;
    u32* b32 = (u32*)B_lds;
    for (int s = tid; s < 4096; s += 256){
      int row = s >> 5, col = s & 31;
      int g = col >> 2, c2 = col & 3;
      b32[row*32 + ((g ^ (row & 7))*4 + c2)] = g32[s];
    }
  }

  // ---- A_sum^T B-fragments in registers: bfw[wt], lane holds B[w=lr+16wt][v=lq*8+j] ----
  s8v bfw[2];
  #pragma unroll
  for (int wt = 0; wt < 2; ++wt){
    u16 tmp[8];
    int w = lr + 16*wt;
    #pragma unroll
    for (int j = 0; j < 8; ++j){
      int v = lq*8 + j;
      tmp[j] = (w < VV && v < VV) ? f2b(Asum[v*VV + w]) : (u16)0;
    }
    bfw[wt] = *(s8v*)tmp;
  }

  // ---- agg via MFMA with register-direct A: 28 tasks (7 it x 4 ct) over 4 waves ----
  #pragma unroll
  for (int tt = 0; tt < 7; ++tt){
    int tau = tt*4 + wv;
    int it = tau >> 2, ct = tau & 3;
    int t  = t0 + it;
    int c  = ct*16 + lr;
    const float* xp = x + ((size_t)(n*CC + c)*TT + t)*VV + lq*8;
    float4 xa = make_float4(0.f,0.f,0.f,0.f), xb = xa;
    float x24 = 0.f;
    if (t < TT){
      if (lq < 3){
        xa = *(const float4*)xp;
        xb = *(const float4*)(xp + 4);
      } else {
        x24 = xp[0];
      }
    }
    u16 pk[8];
    if (lq < 3){
      pk[0]=f2b(xa.x); pk[1]=f2b(xa.y); pk[2]=f2b(xa.z); pk[3]=f2b(xa.w);
      pk[4]=f2b(xb.x); pk[5]=f2b(xb.y); pk[6]=f2b(xb.z); pk[7]=f2b(xb.w);
    } else {
      pk[0]=f2b(x24); pk[1]=0; pk[2]=0; pk[3]=0; pk[4]=0; pk[5]=0; pk[6]=0; pk[7]=0;
    }
    s8v af = *(s8v*)pk;
    f4v d0 = (f4v)(0.f), d1 = (f4v)(0.f);
    d0 = __builtin_amdgcn_mfma_f32_16x16x32_bf16(af, bfw[0], d0, 0, 0, 0);
    d1 = __builtin_amdgcn_mfma_f32_16x16x32_bf16(af, bfw[1], d1, 0, 0, 0);
    int cb = ct*16 + lq*4;
    int g  = cb >> 3, co = cb & 7;
    int ml0 = it*VV + lr - r0;                    // w = lr
    if (ml0 >= 0 && ml0 < 128){
      u16 q[4];
      #pragma unroll
      for (int rg = 0; rg < 4; ++rg) q[rg] = f2b(d0[rg]);
      *(h4v*)&A_lds[ml0*64 + ((g ^ (ml0 & 7))*8) + co] = *(h4v*)q;
    }
    int w1 = lr + 16;
    int ml1 = it*VV + w1 - r0;
    if (w1 < VV && ml1 >= 0 && ml1 < 128){
      u16 q[4];
      #pragma unroll
      for (int rg = 0; rg < 4; ++rg) q[rg] = f2b(d1[rg]);
      *(h4v*)&A_lds[ml1*64 + ((g ^ (ml1 & 7))*8) + co] = *(h4v*)q;
    }
  }
  __syncthreads();

  // ---- main GEMM: 64m x 64o per wave, K=64 (2 substeps) ----
  f4v acc[4][4];
  #pragma unroll
  for (int mi = 0; mi < 4; ++mi)
    #pragma unroll
    for (int ni = 0; ni < 4; ++ni) acc[mi][ni] = (f4v)(0.f);
  #pragma unroll
  for (int ks = 0; ks < 2; ++ks){
    int p = ((ks*4 + lq) ^ (lane & 7)) * 8;
    s8v af[4], bf[4];
    #pragma unroll
    for (int mi = 0; mi < 4; ++mi)
      af[mi] = *(const s8v*)&A_lds[(wm + mi*16 + lr)*64 + p];
    #pragma unroll
    for (int ni = 0; ni < 4; ++ni)
      bf[ni] = *(const s8v*)&B_lds[(wo + ni*16 + lr)*64 + p];
    #pragma unroll
    for (int mi = 0; mi < 4; ++mi)
      #pragma unroll
      for (int ni = 0; ni < 4; ++ni)
        acc[mi][ni] = __builtin_amdgcn_mfma_f32_16x16x32_bf16(af[mi], bf[ni], acc[mi][ni], 0, 0, 0);
  }

  float bias[4];
  #pragma unroll
  for (int ni = 0; ni < 4; ++ni) bias[ni] = gb[wo + ni*16 + lr];
  #pragma unroll
  for (int mi = 0; mi < 4; ++mi){
    int mr = m0 + wm + mi*16 + lq*4;
    #pragma unroll
    for (int ni = 0; ni < 4; ++ni){
      int o = wo + ni*16 + lr;
      #pragma unroll
      for (int rg = 0; rg < 4; ++rg){
        int m = mr + rg;
        if (m < MM)
          xg[((size_t)n*MM + m)*OO + o] = f2b(acc[mi][ni][rg] + bias[ni]);
      }
    }
  }
}

// ---------------- tcn as MFMA implicit GEMM + fused BN partial stats ----------------
// v6 = R2 structure (measured 56.5 us, 0 bank conflicts) + chunked XCD swizzle.
// K-step 64 (18 steps), 512 threads (8 waves: 4 m-strips x 2 o-halves), LDS 2x16+2x16 KB,
// counted vmcnt(4) 1-deep prefetch. K-64 keeps each 128 B xg line within ONE step
// (K-32 split lines across steps -> +52 MB FETCH, R4/R5 lesson).
__global__ __launch_bounds__(512, 4) void k_tcnm(const u16* __restrict__ xg, const u16* __restrict__ Wq2,
                                                 const float* __restrict__ tb, const u16* __restrict__ zbuf,
                                                 u16* __restrict__ xt, float* __restrict__ psum,
                                                 float* __restrict__ psq){
  __shared__ __align__(16) u16 A_lds[2][128*64];   // 2 x 16 KB
  __shared__ __align__(16) u16 B_lds[2][128*64];   // 2 x 16 KB
  __shared__ float sredS[8][64];
  __shared__ float sredQ[8][64];
  int bx = blockIdx.x;
  int lg = ((bx & 7) * 120) + (bx >> 3);   // bijective: 960 = 8 * 120; XCD owns 4 n's
  int n  = lg / 30;
  int m0 = (lg % 30) * 128;
  int tid = threadIdx.x;
  int lane = tid & 63, wv = tid >> 6;
  int wm = (wv >> 1) * 32, wo = (wv & 1) * 64;   // 8 waves: 4 m-strips x 2 o-halves
  int lr = lane & 15, lq = lane >> 4;

  int rlow = tid >> 3;                 // 0..63: row within 64-row half-tile
  int gsrc = (tid & 7) ^ (rlow & 7);
  int tid16 = tid * 16;
  int  tbse[2], vr[2]; bool vm[2];
  #pragma unroll
  for (int it = 0; it < 2; ++it){
    int m = m0 + it*64 + rlow;
    vm[it] = (m < M2);
    int t2 = m / VV, v = m - t2*VV;
    tbse[it] = 2*t2 - 4;
    vr[it] = v;
  }
  size_t basen = (size_t)n*MM*OO + (size_t)gsrc*8;

  f4v acc[2][4];
  #pragma unroll
  for (int mi = 0; mi < 2; ++mi)
    #pragma unroll
    for (int ni = 0; ni < 4; ++ni) acc[mi][ni] = (f4v)(0.f);

  // 4 global_load_lds per thread per K-step (2 A halves + 2 B halves)
  auto stage = [&](int kc, int b){
    int k  = kc >> 1;
    int i0 = (kc & 1) * 64;
    const u16* wbase = Wq2 + kc*8192;
    char* Ab = (char*)(&A_lds[b][0]);
    char* Bb = (char*)(&B_lds[b][0]);
    #pragma unroll
    for (int it = 0; it < 2; ++it){
      int t = tbse[it] + k;
      const u16* ga = (vm[it] && t >= 0 && t < TT)
                      ? xg + basen + (size_t)(t*VV + vr[it])*OO + i0
                      : zbuf;
      async16(ga, Ab + it*8192 + tid16);
      async16(wbase + ((it*64 + rlow)*64 + gsrc*8), Bb + it*8192 + tid16);
    }
  };

  stage(0, 0);                         // prologue: tile 0 in flight (4 loads/thread)
  for (int kc = 0; kc < 18; ++kc){
    int cur = kc & 1;
    if (kc < 17){
      stage(kc + 1, cur ^ 1);          // 8 outstanding per thread
      asm volatile("s_waitcnt vmcnt(4)" ::: "memory");   // cur's 4 landed; next 4 in flight
    } else {
      asm volatile("s_waitcnt vmcnt(0)" ::: "memory");   // last tile: drain
    }
    __builtin_amdgcn_s_barrier();      // all waves' cur-tile loads visible
    asm volatile("" ::: "memory");     // fence: keep ds_reads below the barrier

    const u16* Ac = &A_lds[cur][0];
    const u16* Bc = &B_lds[cur][0];
    #pragma unroll
    for (int ks = 0; ks < 2; ++ks){
      int p = ((ks*4 + lq) ^ (lane & 7)) * 8;
      s8v af[2], bf[4];
      #pragma unroll
      for (int mi = 0; mi < 2; ++mi)
        af[mi] = *(const s8v*)&Ac[(wm + mi*16 + lr)*64 + p];
      #pragma unroll
      for (int ni = 0; ni < 4; ++ni)
        bf[ni] = *(const s8v*)&Bc[(wo + ni*16 + lr)*64 + p];
      #pragma unroll
      for (int mi = 0; mi < 2; ++mi)
        #pragma unroll
        for (int ni = 0; ni < 4; ++ni)
          acc[mi][ni] = __builtin_amdgcn_mfma_f32_16x16x32_bf16(af[mi], bf[ni], acc[mi][ni], 0, 0, 0);
    }
    asm volatile("s_waitcnt lgkmcnt(0)" ::: "memory");   // reads complete before crossing
    __builtin_amdgcn_s_barrier();      // all waves done reading cur -> safe to overwrite
    asm volatile("" ::: "memory");
  }

  float bias[4];
  #pragma unroll
  for (int ni = 0; ni < 4; ++ni) bias[ni] = tb[wo + ni*16 + lr];
  float sni[4] = {0.f,0.f,0.f,0.f}, qni[4] = {0.f,0.f,0.f,0.f};
  #pragma unroll
  for (int mi = 0; mi < 2; ++mi){
    int mr = m0 + wm + mi*16 + lq*4;
    #pragma unroll
    for (int ni = 0; ni < 4; ++ni){
      int o = wo + ni*16 + lr;
      #pragma unroll
      for (int rg = 0; rg < 4; ++rg){
        int mm = mr + rg;
        if (mm < M2){
          float val = acc[mi][ni][rg] + bias[ni];
          xt[((size_t)n*M2 + mm)*OO + o] = f2b(val);
          sni[ni] += val;
          qni[ni] += val*val;
        }
      }
    }
  }
  // cross-lq reduce (lanes differ by 16/32), then cross-wave combine via LDS
  #pragma unroll
  for (int ni = 0; ni < 4; ++ni){
    float s = sni[ni], q = qni[ni];
    s += __shfl_xor(s, 16); s += __shfl_xor(s, 32);
    q += __shfl_xor(q, 16); q += __shfl_xor(q, 32);
    if (lane < 16){
      sredS[wv][ni*16 + lane] = s;
      sredQ[wv][ni*16 + lane] = q;
    }
  }
  __syncthreads();
  // waves with (wv&1) == (o>>6) cover output column o; 4 such waves each
  if (tid < 128){
    int o = tid, h = o >> 6, lo = o & 63;
    psum[(size_t)lg*128 + o] = (sredS[h][lo] + sredS[h+2][lo]) + (sredS[h+4][lo] + sredS[h+6][lo]);
  } else if (tid < 256){
    int o = tid - 128, h = o >> 6, lo = o & 63;
    psq [(size_t)lg*128 + o] = (sredQ[h][lo] + sredQ[h+2][lo]) + (sredQ[h+4][lo] + sredQ[h+6][lo]);
  }
}

// ---------------- BN stats finalize, stage a: 60 blocks reduce 16 partial rows each ----------------
__global__ __launch_bounds__(256) void k_stats2a(const float* __restrict__ psum, const float* __restrict__ psq,
                                                 float* __restrict__ ps2, float* __restrict__ pq2){
  __shared__ float bufS[256], bufQ[256];
  int tid = threadIdx.x, b = blockIdx.x;
  int o = tid & 127, h = tid >> 7;
  float s = 0.f, q = 0.f;
  for (int r = b*16 + h; r < b*16 + 16; r += 2){
    s += psum[(size_t)r*128 + o];
    q += psq [(size_t)r*128 + o];
  }
  bufS[tid] = s; bufQ[tid] = q;
  __syncthreads();
  if (tid < 128){
    ps2[(size_t)b*128 + o] = bufS[tid] + bufS[tid + 128];
    pq2[(size_t)b*128 + o] = bufQ[tid] + bufQ[tid + 128];
  }
}

// ---------------- BN stats finalize, stage b: reduce 60 level-2 rows ----------------
__global__ __launch_bounds__(256) void k_stats2b(const float* __restrict__ ps2, const float* __restrict__ pq2,
                                                 const float* __restrict__ gamma, const float* __restrict__ beta,
                                                 float* __restrict__ stats){
  __shared__ float bufS[256], bufQ[256];
  int tid = threadIdx.x;
  int o = tid & 127, h = tid >> 7;
  float s = 0.f, q = 0.f;
  for (int b = h; b < 60; b += 2){
    s += ps2[(size_t)b*128 + o];
    q += pq2[(size_t)b*128 + o];
  }
  bufS[tid] = s; bufQ[tid] = q;
  __syncthreads();
  if (tid < 128){
    s = bufS[tid] + bufS[tid + 128];
    q = bufQ[tid] + bufQ[tid + 128];
    const float inv = 1.f / 120000.f;
    float mean = s * inv;
    float var  = q * inv - mean*mean;
    float sc = gamma[o] * rsqrtf(var + 1e-5f);
    stats[o]       = sc;
    stats[128 + o] = beta[o] - mean * sc;
  }
}

// ---------------- res as MFMA implicit GEMM + BN + relu: M=(t2*25+v), N=128 o, K=64 c ----------------
// out[n][o][m] with m = t2*25+v  (== reference (N,O,T2,V))
// v4: coalesced output via LDS transpose (store loop covers all 64 rows: 16 iter x 4 rows).
__global__ __launch_bounds__(256, 4) void k_resm(const float* __restrict__ x, const u16* __restrict__ rwb,
                                                 const float* __restrict__ rb, const u16* __restrict__ xt,
                                                 const float* __restrict__ stats, float* __restrict__ out){
  __shared__ __align__(16) char smem[64*130*4];   // 33280 B: staging (32 KB) then transpose buf
  u16* A_lds = (u16*)smem;                        // [128*64]
  u16* B_lds = A_lds + 128*64;                    // [128*64]
  float* tbuf = (float*)smem;                     // [64][130] f32, aliases A/B after GEMM
  int bx = blockIdx.x;
  int n  = bx / 30;
  int m0 = (bx % 30) * 128;
  int t20 = m0 / VV, r0 = m0 % VV;
  int tid = threadIdx.x;
  int lane = tid & 63, wv = tid >> 6;
  int wm = (wv & 1) * 64, wo = (wv >> 1) * 64;
  int lr = lane & 15, lq = lane >> 4;

  {
    const u32* g32 = (const u32*)rwb;
    u32* b32 = (u32*)B_lds;
    for (int s = tid; s < 4096; s += 256){
      int row = s >> 5, col = s & 31;
      int g = col >> 2, c2 = col & 3;
      b32[row*32 + ((g ^ (row & 7))*4 + c2)] = g32[s];
    }
  }

  // stage A: tasks (cg, t2i, v): 8 c's packed into one ds_write_b128
  for (int task = tid; task < 8*7*VV; task += 256){
    int cg  = task / (7*VV);
    int rem = task - cg*(7*VV);
    int t2i = rem / VV, v = rem - t2i*VV;
    int t2 = t20 + t2i;
    int ml = t2i*VV + v - r0;
    if (ml >= 0 && ml < 128){
      u16 pk[8];
      if (t2 < TO){
        const float* xp = x + ((size_t)(n*CC + cg*8)*TT + 2*t2)*VV + v;
        #pragma unroll
        for (int cc = 0; cc < 8; ++cc) pk[cc] = f2b(xp[(size_t)cc*(TT*VV)]);
      } else {
        #pragma unroll
        for (int cc = 0; cc < 8; ++cc) pk[cc] = 0;
      }
      *(h8v*)&A_lds[ml*64 + ((cg ^ (ml & 7))*8)] = *(h8v*)pk;
    }
  }
  __syncthreads();

  f4v acc[4][4];
  #pragma unroll
  for (int mi = 0; mi < 4; ++mi)
    #pragma unroll
    for (int ni = 0; ni < 4; ++ni) acc[mi][ni] = (f4v)(0.f);
  #pragma unroll
  for (int ks = 0; ks < 2; ++ks){
    int p = ((ks*4 + lq) ^ (lane & 7)) * 8;
    s8v af[4], bf[4];
    #pragma unroll
    for (int mi = 0; mi < 4; ++mi)
      af[mi] = *(const s8v*)&A_lds[(wm + mi*16 + lr)*64 + p];
    #pragma unroll
    for (int ni = 0; ni < 4; ++ni)
      bf[ni] = *(const s8v*)&B_lds[(wo + ni*16 + lr)*64 + p];
    #pragma unroll
    for (int mi = 0; mi < 4; ++mi)
      #pragma unroll
      for (int ni = 0; ni < 4; ++ni)
        acc[mi][ni] = __builtin_amdgcn_mfma_f32_16x16x32_bf16(af[mi], bf[ni], acc[mi][ni], 0, 0, 0);
  }

  float sc[4], sb[4], rr[4];
  #pragma unroll
  for (int ni = 0; ni < 4; ++ni){
    int o = wo + ni*16 + lr;
    sc[ni] = stats[o]; sb[ni] = stats[128 + o]; rr[ni] = rb[o];
  }

  // ---- pass p: waves with wo==64p compute+deposit their o-half into tbuf; all store ----
  #pragma unroll
  for (int pass = 0; pass < 2; ++pass){
    __syncthreads();   // pass0: GEMM ds_reads done (smem reuse); pass1: prev stores done
    if ((wv >> 1) == pass){
      #pragma unroll
      for (int mi = 0; mi < 4; ++mi){
        int mb   = m0 + wm + mi*16 + lq*4;
        int mloc = wm + mi*16 + lq*4;
        #pragma unroll
        for (int ni = 0; ni < 4; ++ni){
          int o    = wo + ni*16 + lr;
          int oloc = ni*16 + lr;
          size_t xb = ((size_t)n*M2 + mb)*OO + o;
          float v2[4];
          #pragma unroll
          for (int rg = 0; rg < 4; ++rg){
            float val = 0.f;
            if (mb + rg < M2)
              val = fmaxf(sc[ni]*b2f(xt[xb + (size_t)rg*OO]) + sb[ni] + acc[mi][ni][rg] + rr[ni], 0.f);
            v2[rg] = val;
          }
          *(float2*)&tbuf[oloc*130 + mloc]     = make_float2(v2[0], v2[1]);
          *(float2*)&tbuf[oloc*130 + mloc + 2] = make_float2(v2[2], v2[3]);
        }
      }
    }
    __syncthreads();
    // cooperative coalesced store: 64 rows x 128 f32, float2 per lane, 4 rows/iter x 16
    #pragma unroll
    for (int it = 0; it < 16; ++it){
      int row = it*4 + (tid >> 6);        // 4 rows/iter, 64 lanes/row
      int c2  = (tid & 63) * 2;
      int o   = pass*64 + row;
      int mg  = m0 + c2;
      size_t ob = ((size_t)(n*OO + o))*M2 + mg;
      float2 vv = *(float2*)&tbuf[row*130 + c2];
      if (mg + 1 < M2)      *(float2*)&out[ob] = vv;
      else if (mg < M2)     out[ob] = vv.x;
    }
  }
}

extern "C" void kernel_launch(void* const* d_in, const int* in_sizes, int n_in,
                              void* d_out, int out_size, void* d_ws, size_t ws_size,
                              hipStream_t stream) {
  const float* x     = (const float*)d_in[0];
  const float* Ap    = (const float*)d_in[1];
  const float* ei    = (const float*)d_in[2];
  const float* gw    = (const float*)d_in[3];
  const float* gb    = (const float*)d_in[4];
  const float* tw    = (const float*)d_in[5];
  const float* tb    = (const float*)d_in[6];
  const float* gamma = (const float*)d_in[7];
  const float* beta  = (const float*)d_in[8];
  const float* rw    = (const float*)d_in[9];
  const float* rb    = (const float*)d_in[10];
  float* out = (float*)d_out;

  char* ws = (char*)d_ws;
  float* Asum  = (float*)ws;                      // 2500 B
  float* zbuf  = (float*)(ws + 2560);             // 512 B zero page
  u16*   Wq2   = (u16*)(ws + 4096);               // 294912 B -> 299008
  u16*   gwb   = (u16*)(ws + 299008);             // 16384 B  -> 315392
  u16*   rwb   = (u16*)(ws + 315392);             // 16384 B  -> 331776
  float* stats = (float*)(ws + 331776);           // 1024 B   -> 332800
  float* psum  = (float*)(ws + 333824);           // 491520 B -> 825344
  float* psq   = (float*)(ws + 825344);           // 491520 B -> 1316864
  float* ps2   = (float*)(ws + 1316864);          // 30720 B  -> 1347584
  float* pq2   = (float*)(ws + 1347584);          // 30720 B  -> 1378304
  u16*   xg    = (u16*)(ws + (2u<<20));           // 61,440,000 B [n][m=t*25+v][o] bf16
  u16*   xt    = (u16*)(ws + 63537152);           // 28,800,000 B [n][m=t2*25+v][o] bf16 (~92.3 MB total)

  k_prep   <<<dim3(644),    dim3(256), 0, stream>>>(Ap, ei, tw, gw, rw, Asum, zbuf, Wq2, gwb, rwb);
  k_gcnm   <<<dim3(NB*MT),  dim3(256), 0, stream>>>(x, Asum, gwb, gb, xg);
  k_tcnm   <<<dim3(NB*30),  dim3(512), 0, stream>>>(xg, Wq2, tb, (const u16*)zbuf, xt, psum, psq);
  k_stats2a<<<dim3(60),     dim3(256), 0, stream>>>(psum, psq, ps2, pq2);
  k_stats2b<<<dim3(1),      dim3(256), 0, stream>>>(ps2, pq2, gamma, beta, stats);
  k_resm   <<<dim3(NB*30),  dim3(256), 0, stream>>>(x, rwb, rb, xt, stats, out);
}

// Round 7
// 269.166 us; speedup vs baseline: 1.0587x; 1.0018x over previous
//
#include <hip/hip_runtime.h>
#include <hip/hip_bf16.h>

typedef unsigned short u16;
typedef unsigned int   u32;

#define NB 32
#define CC 64
#define TT 300
#define VV 25
#define OO 128
#define TO 150
#define KT 9
#define MM 7500          // T*V rows per n (gcn GEMM)
#define MT 59            // ceil(7500/128)
#define M2 3750          // T2*V rows per n (tcn/res GEMMs)

typedef short s8v  __attribute__((ext_vector_type(8)));
typedef float f4v  __attribute__((ext_vector_type(4)));
typedef u16  h4v  __attribute__((ext_vector_type(4)));
typedef u16  h8v  __attribute__((ext_vector_type(8)));

__device__ __forceinline__ float b2f(u16 u){
  union { u32 i; float f; } c; c.i = ((u32)u) << 16; return c.f;
}
__device__ __forceinline__ u16 f2b(float f){
  __hip_bfloat16 h = __float2bfloat16(f);
  return *reinterpret_cast<u16*>(&h);
}
__device__ __forceinline__ void async16(const void* g, void* l){
  __builtin_amdgcn_global_load_lds((const __attribute__((address_space(1))) u32*)g,
                                   (__attribute__((address_space(3))) u32*)l, 16, 0, 0);
}

// ---------------- prep: A_sum + zero-page + tcn_w repack + gcn_w/res_w bf16 ----------------
// Wq2 layout (K-64): kc = k*2 + half (kc<18), Wq2[kc][o][j] = tcn_w[o][(kc&1)*64+j][k], j<64.
__global__ __launch_bounds__(256) void k_prep(const float* __restrict__ Ap, const float* __restrict__ ei,
                                              const float* __restrict__ tw, const float* __restrict__ gw,
                                              const float* __restrict__ rw,
                                              float* __restrict__ Asum, float* __restrict__ zbuf,
                                              u16* __restrict__ Wq2, u16* __restrict__ gwb,
                                              u16* __restrict__ rwb){
  int idx = blockIdx.x * 256 + threadIdx.x;
  if (idx < VV*VV){
    float s = 0.f;
    for (int p = 0; p < 3; ++p) s += ei[p] * Ap[p*VV*VV + idx];
    Asum[idx] = s;
  }
  if (idx >= 640 && idx < 768) zbuf[idx - 640] = 0.f;   // 512 B zero page
  int w = idx - 1024;
  if (w >= 0 && w < 18*OO*64){
    int kc = w >> 13;
    int r  = w & 8191;
    int o  = r >> 6;
    int j  = r & 63;
    int k  = kc >> 1;
    int i  = (kc & 1)*64 + j;
    Wq2[w] = f2b(tw[o*(OO*KT) + i*KT + k]);   // Wq2[kc][o][j] = tcn_w[o][i][k]
  }
  int w2 = idx - 148480;
  if (w2 >= 0 && w2 < OO*CC) gwb[w2] = f2b(gw[w2]);   // gwb[o][c]
  int w3 = idx - 156672;
  if (w3 >= 0 && w3 < OO*CC) rwb[w3] = f2b(rw[w3]);   // rwb[o][c]
}

// ---------------- gcn: register-direct MFMA agg + MFMA GEMM: M=(t*25+v), N=128 o, K=64 c ----------------
// xg layout: [n][m=t*25+v][o].  LDS = 32 KB; no x staging buffer.
// v7: bulk-issued loads. R6 counters (MfmaUtil 3.6%, VALUBusy 18%, ~85k cyc/block) showed
// serialized load latency: VGPR=60 proves the 7 agg tasks' loads were not hoisted.
// Now: load-only loop (14 independent dwordx4 in flight, clamped addresses, masks applied
// at convert time — identical semantics), then consume loop. Stage-B likewise batched.
__global__ __launch_bounds__(256, 4) void k_gcnm(const float* __restrict__ x, const float* __restrict__ Asum,
                                                 const u16* __restrict__ gwb, const float* __restrict__ gb,
                                                 u16* __restrict__ xg){
  __shared__ __align__(16) u16 A_lds[128*64];   // 16 KB, XOR-swizzled granules
  __shared__ __align__(16) u16 B_lds[128*64];   // 16 KB, XOR-swizzled granules
  int bx = blockIdx.x;
  int n  = bx / MT;
  int m0 = (bx % MT) * 128;
  int t0 = m0 / VV, r0 = m0 % VV;
  int tid = threadIdx.x;
  int lane = tid & 63, wv = tid >> 6;
  int wm = (wv & 1) * 64, wo = (wv >> 1) * 64;
  int lr = lane & 15, lq = lane >> 4;

  // ---- stage B (gwb, 16 KB): batch 16 loads, then 16 swizzled ds_writes ----
  {
    const u32* g32 = (const u32*)gwb;
    u32 tmp[16];
    #pragma unroll
    for (int i = 0; i < 16; ++i) tmp[i] = g32[tid + i*256];
    u32* b32 = (u32*)B_lds;
    #pragma unroll
    for (int i = 0; i < 16; ++i){
      int s = tid + i*256;
      int row = s >> 5, col = s & 31;
      int g = col >> 2, c2 = col & 3;
      b32[row*32 + ((g ^ (row & 7))*4 + c2)] = tmp[i];
    }
  }

  // ---- bulk-issue all 7 agg tasks' x loads (clamped, unconditional per lq-path) ----
  const size_t XTOT = (size_t)NB*CC*TT*VV;   // 15,360,000 floats
  float4 xa7[7], xb7[7];
  #pragma unroll
  for (int tt = 0; tt < 7; ++tt){
    int tau = tt*4 + wv;
    int it = tau >> 2, ct = tau & 3;
    int t  = t0 + it;
    int c  = ct*16 + lr;
    size_t off = ((size_t)(n*CC + c)*TT + t)*VV + lq*8;
    if (lq < 3){
      // valid (t<TT) lq<3 reads are always in-bounds (v<=23 -> off+7 within row);
      // clamp only protects the masked t>=TT tail reads.
      if (off > XTOT - 8) off = XTOT - 8;
      const float* xp = x + off;
      xa7[tt] = *(const float4*)xp;
      xb7[tt] = *(const float4*)(xp + 4);
    } else {
      if (off > XTOT - 1) off = XTOT - 1;
      xa7[tt].x = x[off];    // v=24 scalar; rest of xa7/xb7 unused for lq==3
    }
  }

  // ---- A_sum^T B-fragments in registers: bfw[wt], lane holds B[w=lr+16wt][v=lq*8+j] ----
  s8v bfw[2];
  #pragma unroll
  for (int wt = 0; wt < 2; ++wt){
    u16 tmp[8];
    int w = lr + 16*wt;
    #pragma unroll
    for (int j = 0; j < 8; ++j){
      int v = lq*8 + j;
      tmp[j] = (w < VV && v < VV) ? f2b(Asum[v*VV + w]) : (u16)0;
    }
    bfw[wt] = *(s8v*)tmp;
  }

  // ---- consume: convert + MFMA + swizzled LDS write, 7 tasks over 4 waves ----
  #pragma unroll
  for (int tt = 0; tt < 7; ++tt){
    int tau = tt*4 + wv;
    int it = tau >> 2, ct = tau & 3;
    int t  = t0 + it;
    bool valid = (t < TT);
    u16 pk[8];
    if (lq < 3){
      if (valid){
        pk[0]=f2b(xa7[tt].x); pk[1]=f2b(xa7[tt].y); pk[2]=f2b(xa7[tt].z); pk[3]=f2b(xa7[tt].w);
        pk[4]=f2b(xb7[tt].x); pk[5]=f2b(xb7[tt].y); pk[6]=f2b(xb7[tt].z); pk[7]=f2b(xb7[tt].w);
      } else {
        #pragma unroll
        for (int j = 0; j < 8; ++j) pk[j] = 0;
      }
    } else {
      pk[0] = valid ? f2b(xa7[tt].x) : (u16)0;
      pk[1]=0; pk[2]=0; pk[3]=0; pk[4]=0; pk[5]=0; pk[6]=0; pk[7]=0;
    }
    s8v af = *(s8v*)pk;
    f4v d0 = (f4v)(0.f), d1 = (f4v)(0.f);
    d0 = __builtin_amdgcn_mfma_f32_16x16x32_bf16(af, bfw[0], d0, 0, 0, 0);
    d1 = __builtin_amdgcn_mfma_f32_16x16x32_bf16(af, bfw[1], d1, 0, 0, 0);
    int cb = ct*16 + lq*4;
    int g  = cb >> 3, co = cb & 7;
    int ml0 = it*VV + lr - r0;                    // w = lr
    if (ml0 >= 0 && ml0 < 128){
      u16 q[4];
      #pragma unroll
      for (int rg = 0; rg < 4; ++rg) q[rg] = f2b(d0[rg]);
      *(h4v*)&A_lds[ml0*64 + ((g ^ (ml0 & 7))*8) + co] = *(h4v*)q;
    }
    int w1 = lr + 16;
    int ml1 = it*VV + w1 - r0;
    if (w1 < VV && ml1 >= 0 && ml1 < 128){
      u16 q[4];
      #pragma unroll
      for (int rg = 0; rg < 4; ++rg) q[rg] = f2b(d1[rg]);
      *(h4v*)&A_lds[ml1*64 + ((g ^ (ml1 & 7))*8) + co] = *(h4v*)q;
    }
  }
  __syncthreads();

  // ---- main GEMM: 64m x 64o per wave, K=64 (2 substeps) ----
  f4v acc[4][4];
  #pragma unroll
  for (int mi = 0; mi < 4; ++mi)
    #pragma unroll
    for (int ni = 0; ni < 4; ++ni) acc[mi][ni] = (f4v)(0.f);
  #pragma unroll
  for (int ks = 0; ks < 2; ++ks){
    int p = ((ks*4 + lq) ^ (lane & 7)) * 8;
    s8v af[4], bf[4];
    #pragma unroll
    for (int mi = 0; mi < 4; ++mi)
      af[mi] = *(const s8v*)&A_lds[(wm + mi*16 + lr)*64 + p];
    #pragma unroll
    for (int ni = 0; ni < 4; ++ni)
      bf[ni] = *(const s8v*)&B_lds[(wo + ni*16 + lr)*64 + p];
    #pragma unroll
    for (int mi = 0; mi < 4; ++mi)
      #pragma unroll
      for (int ni = 0; ni < 4; ++ni)
        acc[mi][ni] = __builtin_amdgcn_mfma_f32_16x16x32_bf16(af[mi], bf[ni], acc[mi][ni], 0, 0, 0);
  }

  float bias[4];
  #pragma unroll
  for (int ni = 0; ni < 4; ++ni) bias[ni] = gb[wo + ni*16 + lr];
  #pragma unroll
  for (int mi = 0; mi < 4; ++mi){
    int mr = m0 + wm + mi*16 + lq*4;
    #pragma unroll
    for (int ni = 0; ni < 4; ++ni){
      int o = wo + ni*16 + lr;
      #pragma unroll
      for (int rg = 0; rg < 4; ++rg){
        int m = mr + rg;
        if (m < MM)
          xg[((size_t)n*MM + m)*OO + o] = f2b(acc[mi][ni][rg] + bias[ni]);
      }
    }
  }
}

// ---------------- tcn as MFMA implicit GEMM + fused BN partial stats ----------------
// v6 = R2 structure (measured 56.5 us, 0 bank conflicts) + chunked XCD swizzle.
// K-step 64 (18 steps), 512 threads (8 waves: 4 m-strips x 2 o-halves), LDS 2x16+2x16 KB,
// counted vmcnt(4) 1-deep prefetch. K-64 keeps each 128 B xg line within ONE step
// (K-32 split lines across steps -> +52 MB FETCH, R4/R5 lesson).
__global__ __launch_bounds__(512, 4) void k_tcnm(const u16* __restrict__ xg, const u16* __restrict__ Wq2,
                                                 const float* __restrict__ tb, const u16* __restrict__ zbuf,
                                                 u16* __restrict__ xt, float* __restrict__ psum,
                                                 float* __restrict__ psq){
  __shared__ __align__(16) u16 A_lds[2][128*64];   // 2 x 16 KB
  __shared__ __align__(16) u16 B_lds[2][128*64];   // 2 x 16 KB
  __shared__ float sredS[8][64];
  __shared__ float sredQ[8][64];
  int bx = blockIdx.x;
  int lg = ((bx & 7) * 120) + (bx >> 3);   // bijective: 960 = 8 * 120; XCD owns 4 n's
  int n  = lg / 30;
  int m0 = (lg % 30) * 128;
  int tid = threadIdx.x;
  int lane = tid & 63, wv = tid >> 6;
  int wm = (wv >> 1) * 32, wo = (wv & 1) * 64;   // 8 waves: 4 m-strips x 2 o-halves
  int lr = lane & 15, lq = lane >> 4;

  int rlow = tid >> 3;                 // 0..63: row within 64-row half-tile
  int gsrc = (tid & 7) ^ (rlow & 7);
  int tid16 = tid * 16;
  int  tbse[2], vr[2]; bool vm[2];
  #pragma unroll
  for (int it = 0; it < 2; ++it){
    int m = m0 + it*64 + rlow;
    vm[it] = (m < M2);
    int t2 = m / VV, v = m - t2*VV;
    tbse[it] = 2*t2 - 4;
    vr[it] = v;
  }
  size_t basen = (size_t)n*MM*OO + (size_t)gsrc*8;

  f4v acc[2][4];
  #pragma unroll
  for (int mi = 0; mi < 2; ++mi)
    #pragma unroll
    for (int ni = 0; ni < 4; ++ni) acc[mi][ni] = (f4v)(0.f);

  // 4 global_load_lds per thread per K-step (2 A halves + 2 B halves)
  auto stage = [&](int kc, int b){
    int k  = kc >> 1;
    int i0 = (kc & 1) * 64;
    const u16* wbase = Wq2 + kc*8192;
    char* Ab = (char*)(&A_lds[b][0]);
    char* Bb = (char*)(&B_lds[b][0]);
    #pragma unroll
    for (int it = 0; it < 2; ++it){
      int t = tbse[it] + k;
      const u16* ga = (vm[it] && t >= 0 && t < TT)
                      ? xg + basen + (size_t)(t*VV + vr[it])*OO + i0
                      : zbuf;
      async16(ga, Ab + it*8192 + tid16);
      async16(wbase + ((it*64 + rlow)*64 + gsrc*8), Bb + it*8192 + tid16);
    }
  };

  stage(0, 0);                         // prologue: tile 0 in flight (4 loads/thread)
  for (int kc = 0; kc < 18; ++kc){
    int cur = kc & 1;
    if (kc < 17){
      stage(kc + 1, cur ^ 1);          // 8 outstanding per thread
      asm volatile("s_waitcnt vmcnt(4)" ::: "memory");   // cur's 4 landed; next 4 in flight
    } else {
      asm volatile("s_waitcnt vmcnt(0)" ::: "memory");   // last tile: drain
    }
    __builtin_amdgcn_s_barrier();      // all waves' cur-tile loads visible
    asm volatile("" ::: "memory");     // fence: keep ds_reads below the barrier

    const u16* Ac = &A_lds[cur][0];
    const u16* Bc = &B_lds[cur][0];
    #pragma unroll
    for (int ks = 0; ks < 2; ++ks){
      int p = ((ks*4 + lq) ^ (lane & 7)) * 8;
      s8v af[2], bf[4];
      #pragma unroll
      for (int mi = 0; mi < 2; ++mi)
        af[mi] = *(const s8v*)&Ac[(wm + mi*16 + lr)*64 + p];
      #pragma unroll
      for (int ni = 0; ni < 4; ++ni)
        bf[ni] = *(const s8v*)&Bc[(wo + ni*16 + lr)*64 + p];
      #pragma unroll
      for (int mi = 0; mi < 2; ++mi)
        #pragma unroll
        for (int ni = 0; ni < 4; ++ni)
          acc[mi][ni] = __builtin_amdgcn_mfma_f32_16x16x32_bf16(af[mi], bf[ni], acc[mi][ni], 0, 0, 0);
    }
    asm volatile("s_waitcnt lgkmcnt(0)" ::: "memory");   // reads complete before crossing
    __builtin_amdgcn_s_barrier();      // all waves done reading cur -> safe to overwrite
    asm volatile("" ::: "memory");
  }

  float bias[4];
  #pragma unroll
  for (int ni = 0; ni < 4; ++ni) bias[ni] = tb[wo + ni*16 + lr];
  float sni[4] = {0.f,0.f,0.f,0.f}, qni[4] = {0.f,0.f,0.f,0.f};
  #pragma unroll
  for (int mi = 0; mi < 2; ++mi){
    int mr = m0 + wm + mi*16 + lq*4;
    #pragma unroll
    for (int ni = 0; ni < 4; ++ni){
      int o = wo + ni*16 + lr;
      #pragma unroll
      for (int rg = 0; rg < 4; ++rg){
        int mm = mr + rg;
        if (mm < M2){
          float val = acc[mi][ni][rg] + bias[ni];
          xt[((size_t)n*M2 + mm)*OO + o] = f2b(val);
          sni[ni] += val;
          qni[ni] += val*val;
        }
      }
    }
  }
  // cross-lq reduce (lanes differ by 16/32), then cross-wave combine via LDS
  #pragma unroll
  for (int ni = 0; ni < 4; ++ni){
    float s = sni[ni], q = qni[ni];
    s += __shfl_xor(s, 16); s += __shfl_xor(s, 32);
    q += __shfl_xor(q, 16); q += __shfl_xor(q, 32);
    if (lane < 16){
      sredS[wv][ni*16 + lane] = s;
      sredQ[wv][ni*16 + lane] = q;
    }
  }
  __syncthreads();
  // waves with (wv&1) == (o>>6) cover output column o; 4 such waves each
  if (tid < 128){
    int o = tid, h = o >> 6, lo = o & 63;
    psum[(size_t)lg*128 + o] = (sredS[h][lo] + sredS[h+2][lo]) + (sredS[h+4][lo] + sredS[h+6][lo]);
  } else if (tid < 256){
    int o = tid - 128, h = o >> 6, lo = o & 63;
    psq [(size_t)lg*128 + o] = (sredQ[h][lo] + sredQ[h+2][lo]) + (sredQ[h+4][lo] + sredQ[h+6][lo]);
  }
}

// ---------------- BN stats finalize, stage a: 60 blocks reduce 16 partial rows each ----------------
__global__ __launch_bounds__(256) void k_stats2a(const float* __restrict__ psum, const float* __restrict__ psq,
                                                 float* __restrict__ ps2, float* __restrict__ pq2){
  __shared__ float bufS[256], bufQ[256];
  int tid = threadIdx.x, b = blockIdx.x;
  int o = tid & 127, h = tid >> 7;
  float s = 0.f, q = 0.f;
  for (int r = b*16 + h; r < b*16 + 16; r += 2){
    s += psum[(size_t)r*128 + o];
    q += psq [(size_t)r*128 + o];
  }
  bufS[tid] = s; bufQ[tid] = q;
  __syncthreads();
  if (tid < 128){
    ps2[(size_t)b*128 + o] = bufS[tid] + bufS[tid + 128];
    pq2[(size_t)b*128 + o] = bufQ[tid] + bufQ[tid + 128];
  }
}

// ---------------- BN stats finalize, stage b: reduce 60 level-2 rows ----------------
__global__ __launch_bounds__(256) void k_stats2b(const float* __restrict__ ps2, const float* __restrict__ pq2,
                                                 const float* __restrict__ gamma, const float* __restrict__ beta,
                                                 float* __restrict__ stats){
  __shared__ float bufS[256], bufQ[256];
  int tid = threadIdx.x;
  int o = tid & 127, h = tid >> 7;
  float s = 0.f, q = 0.f;
  for (int b = h; b < 60; b += 2){
    s += ps2[(size_t)b*128 + o];
    q += pq2[(size_t)b*128 + o];
  }
  bufS[tid] = s; bufQ[tid] = q;
  __syncthreads();
  if (tid < 128){
    s = bufS[tid] + bufS[tid + 128];
    q = bufQ[tid] + bufQ[tid + 128];
    const float inv = 1.f / 120000.f;
    float mean = s * inv;
    float var  = q * inv - mean*mean;
    float sc = gamma[o] * rsqrtf(var + 1e-5f);
    stats[o]       = sc;
    stats[128 + o] = beta[o] - mean * sc;
  }
}

// ---------------- res as MFMA implicit GEMM + BN + relu: M=(t2*25+v), N=128 o, K=64 c ----------------
// out[n][o][m] with m = t2*25+v  (== reference (N,O,T2,V))
// v4: coalesced output via LDS transpose (store loop covers all 64 rows: 16 iter x 4 rows).
__global__ __launch_bounds__(256, 4) void k_resm(const float* __restrict__ x, const u16* __restrict__ rwb,
                                                 const float* __restrict__ rb, const u16* __restrict__ xt,
                                                 const float* __restrict__ stats, float* __restrict__ out){
  __shared__ __align__(16) char smem[64*130*4];   // 33280 B: staging (32 KB) then transpose buf
  u16* A_lds = (u16*)smem;                        // [128*64]
  u16* B_lds = A_lds + 128*64;                    // [128*64]
  float* tbuf = (float*)smem;                     // [64][130] f32, aliases A/B after GEMM
  int bx = blockIdx.x;
  int n  = bx / 30;
  int m0 = (bx % 30) * 128;
  int t20 = m0 / VV, r0 = m0 % VV;
  int tid = threadIdx.x;
  int lane = tid & 63, wv = tid >> 6;
  int wm = (wv & 1) * 64, wo = (wv >> 1) * 64;
  int lr = lane & 15, lq = lane >> 4;

  {
    const u32* g32 = (const u32*)rwb;
    u32* b32 = (u32*)B_lds;
    for (int s = tid; s < 4096; s += 256){
      int row = s >> 5, col = s & 31;
      int g = col >> 2, c2 = col & 3;
      b32[row*32 + ((g ^ (row & 7))*4 + c2)] = g32[s];
    }
  }

  // stage A: tasks (cg, t2i, v): 8 c's packed into one ds_write_b128
  for (int task = tid; task < 8*7*VV; task += 256){
    int cg  = task / (7*VV);
    int rem = task - cg*(7*VV);
    int t2i = rem / VV, v = rem - t2i*VV;
    int t2 = t20 + t2i;
    int ml = t2i*VV + v - r0;
    if (ml >= 0 && ml < 128){
      u16 pk[8];
      if (t2 < TO){
        const float* xp = x + ((size_t)(n*CC + cg*8)*TT + 2*t2)*VV + v;
        #pragma unroll
        for (int cc = 0; cc < 8; ++cc) pk[cc] = f2b(xp[(size_t)cc*(TT*VV)]);
      } else {
        #pragma unroll
        for (int cc = 0; cc < 8; ++cc) pk[cc] = 0;
      }
      *(h8v*)&A_lds[ml*64 + ((cg ^ (ml & 7))*8)] = *(h8v*)pk;
    }
  }
  __syncthreads();

  f4v acc[4][4];
  #pragma unroll
  for (int mi = 0; mi < 4; ++mi)
    #pragma unroll
    for (int ni = 0; ni < 4; ++ni) acc[mi][ni] = (f4v)(0.f);
  #pragma unroll
  for (int ks = 0; ks < 2; ++ks){
    int p = ((ks*4 + lq) ^ (lane & 7)) * 8;
    s8v af[4], bf[4];
    #pragma unroll
    for (int mi = 0; mi < 4; ++mi)
      af[mi] = *(const s8v*)&A_lds[(wm + mi*16 + lr)*64 + p];
    #pragma unroll
    for (int ni = 0; ni < 4; ++ni)
      bf[ni] = *(const s8v*)&B_lds[(wo + ni*16 + lr)*64 + p];
    #pragma unroll
    for (int mi = 0; mi < 4; ++mi)
      #pragma unroll
      for (int ni = 0; ni < 4; ++ni)
        acc[mi][ni] = __builtin_amdgcn_mfma_f32_16x16x32_bf16(af[mi], bf[ni], acc[mi][ni], 0, 0, 0);
  }

  float sc[4], sb[4], rr[4];
  #pragma unroll
  for (int ni = 0; ni < 4; ++ni){
    int o = wo + ni*16 + lr;
    sc[ni] = stats[o]; sb[ni] = stats[128 + o]; rr[ni] = rb[o];
  }

  // ---- pass p: waves with wo==64p compute+deposit their o-half into tbuf; all store ----
  #pragma unroll
  for (int pass = 0; pass < 2; ++pass){
    __syncthreads();   // pass0: GEMM ds_reads done (smem reuse); pass1: prev stores done
    if ((wv >> 1) == pass){
      #pragma unroll
      for (int mi = 0; mi < 4; ++mi){
        int mb   = m0 + wm + mi*16 + lq*4;
        int mloc = wm + mi*16 + lq*4;
        #pragma unroll
        for (int ni = 0; ni < 4; ++ni){
          int o    = wo + ni*16 + lr;
          int oloc = ni*16 + lr;
          size_t xb = ((size_t)n*M2 + mb)*OO + o;
          float v2[4];
          #pragma unroll
          for (int rg = 0; rg < 4; ++rg){
            float val = 0.f;
            if (mb + rg < M2)
              val = fmaxf(sc[ni]*b2f(xt[xb + (size_t)rg*OO]) + sb[ni] + acc[mi][ni][rg] + rr[ni], 0.f);
            v2[rg] = val;
          }
          *(float2*)&tbuf[oloc*130 + mloc]     = make_float2(v2[0], v2[1]);
          *(float2*)&tbuf[oloc*130 + mloc + 2] = make_float2(v2[2], v2[3]);
        }
      }
    }
    __syncthreads();
    // cooperative coalesced store: 64 rows x 128 f32, float2 per lane, 4 rows/iter x 16
    #pragma unroll
    for (int it = 0; it < 16; ++it){
      int row = it*4 + (tid >> 6);        // 4 rows/iter, 64 lanes/row
      int c2  = (tid & 63) * 2;
      int o   = pass*64 + row;
      int mg  = m0 + c2;
      size_t ob = ((size_t)(n*OO + o))*M2 + mg;
      float2 vv = *(float2*)&tbuf[row*130 + c2];
      if (mg + 1 < M2)      *(float2*)&out[ob] = vv;
      else if (mg < M2)     out[ob] = vv.x;
    }
  }
}

extern "C" void kernel_launch(void* const* d_in, const int* in_sizes, int n_in,
                              void* d_out, int out_size, void* d_ws, size_t ws_size,
                              hipStream_t stream) {
  const float* x     = (const float*)d_in[0];
  const float* Ap    = (const float*)d_in[1];
  const float* ei    = (const float*)d_in[2];
  const float* gw    = (const float*)d_in[3];
  const float* gb    = (const float*)d_in[4];
  const float* tw    = (const float*)d_in[5];
  const float* tb    = (const float*)d_in[6];
  const float* gamma = (const float*)d_in[7];
  const float* beta  = (const float*)d_in[8];
  const float* rw    = (const float*)d_in[9];
  const float* rb    = (const float*)d_in[10];
  float* out = (float*)d_out;

  char* ws = (char*)d_ws;
  float* Asum  = (float*)ws;                      // 2500 B
  float* zbuf  = (float*)(ws + 2560);             // 512 B zero page
  u16*   Wq2   = (u16*)(ws + 4096);               // 294912 B -> 299008
  u16*   gwb   = (u16*)(ws + 299008);             // 16384 B  -> 315392
  u16*   rwb   = (u16*)(ws + 315392);             // 16384 B  -> 331776
  float* stats = (float*)(ws + 331776);           // 1024 B   -> 332800
  float* psum  = (float*)(ws + 333824);           // 491520 B -> 825344
  float* psq   = (float*)(ws + 825344);           // 491520 B -> 1316864
  float* ps2   = (float*)(ws + 1316864);          // 30720 B  -> 1347584
  float* pq2   = (float*)(ws + 1347584);          // 30720 B  -> 1378304
  u16*   xg    = (u16*)(ws + (2u<<20));           // 61,440,000 B [n][m=t*25+v][o] bf16
  u16*   xt    = (u16*)(ws + 63537152);           // 28,800,000 B [n][m=t2*25+v][o] bf16 (~92.3 MB total)

  k_prep   <<<dim3(644),    dim3(256), 0, stream>>>(Ap, ei, tw, gw, rw, Asum, zbuf, Wq2, gwb, rwb);
  k_gcnm   <<<dim3(NB*MT),  dim3(256), 0, stream>>>(x, Asum, gwb, gb, xg);
  k_tcnm   <<<dim3(NB*30),  dim3(512), 0, stream>>>(xg, Wq2, tb, (const u16*)zbuf, xt, psum, psq);
  k_stats2a<<<dim3(60),     dim3(256), 0, stream>>>(psum, psq, ps2, pq2);
  k_stats2b<<<dim3(1),      dim3(256), 0, stream>>>(ps2, pq2, gamma, beta, stats);
  k_resm   <<<dim3(NB*30),  dim3(256), 0, stream>>>(x, rwb, rb, xt, stats, out);
}

// Round 10
// 257.748 us; speedup vs baseline: 1.1056x; 1.0443x over previous
//
#include <hip/hip_runtime.h>
#include <hip/hip_bf16.h>

typedef unsigned short u16;
typedef unsigned int   u32;

#define NB 32
#define CC 64
#define TT 300
#define VV 25
#define OO 128
#define TO 150
#define KT 9
#define MM 7500          // T*V rows per n (gcn GEMM)
#define MT 59            // ceil(7500/128)
#define M2 3750          // T2*V rows per n (tcn/res GEMMs)

typedef short s8v  __attribute__((ext_vector_type(8)));
typedef float f4v  __attribute__((ext_vector_type(4)));
typedef u16  h4v  __attribute__((ext_vector_type(4)));
typedef u16  h8v  __attribute__((ext_vector_type(8)));

__device__ __forceinline__ float b2f(u16 u){
  union { u32 i; float f; } c; c.i = ((u32)u) << 16; return c.f;
}
__device__ __forceinline__ u16 f2b(float f){
  __hip_bfloat16 h = __float2bfloat16(f);
  return *reinterpret_cast<u16*>(&h);
}
__device__ __forceinline__ void async16(const void* g, void* l){
  __builtin_amdgcn_global_load_lds((const __attribute__((address_space(1))) u32*)g,
                                   (__attribute__((address_space(3))) u32*)l, 16, 0, 0);
}

// ---------------- prep: A_sum + zero-page + tcn_w repack + gcn_w/res_w bf16 ----------------
// Wq2 layout (K-64): kc = k*2 + half (kc<18), Wq2[kc][o][j] = tcn_w[o][(kc&1)*64+j][k], j<64.
__global__ __launch_bounds__(256) void k_prep(const float* __restrict__ Ap, const float* __restrict__ ei,
                                              const float* __restrict__ tw, const float* __restrict__ gw,
                                              const float* __restrict__ rw,
                                              float* __restrict__ Asum, float* __restrict__ zbuf,
                                              u16* __restrict__ Wq2, u16* __restrict__ gwb,
                                              u16* __restrict__ rwb){
  int idx = blockIdx.x * 256 + threadIdx.x;
  if (idx < VV*VV){
    float s = 0.f;
    for (int p = 0; p < 3; ++p) s += ei[p] * Ap[p*VV*VV + idx];
    Asum[idx] = s;
  }
  if (idx >= 640 && idx < 768) zbuf[idx - 640] = 0.f;   // 512 B zero page
  int w = idx - 1024;
  if (w >= 0 && w < 18*OO*64){
    int kc = w >> 13;
    int r  = w & 8191;
    int o  = r >> 6;
    int j  = r & 63;
    int k  = kc >> 1;
    int i  = (kc & 1)*64 + j;
    Wq2[w] = f2b(tw[o*(OO*KT) + i*KT + k]);   // Wq2[kc][o][j] = tcn_w[o][i][k]
  }
  int w2 = idx - 148480;
  if (w2 >= 0 && w2 < OO*CC) gwb[w2] = f2b(gw[w2]);   // gwb[o][c]
  int w3 = idx - 156672;
  if (w3 >= 0 && w3 < OO*CC) rwb[w3] = f2b(rw[w3]);   // rwb[o][c]
}

// ---------------- gcn: register-direct MFMA agg + MFMA GEMM: M=(t*25+v), N=128 o, K=64 c ----------------
// xg layout: [n][m=t*25+v][o].  LDS = 32 KB; no x staging buffer.
// v10 = v9 with the lq==3 addressing bug fixed (R9 absmax 0.127: clamping off to XTOT-8
// corrupted the single element x[31][63][299][24]). lq==3 now loads at off-7 so the target
// element lands at xb7[tt][3]; valid lanes never hit the clamp (max off = XTOT-8 exactly).
// Structure: (1) stage-B via async16 with pre-swizzled global src; (2) 14 x-loads as
// inline-asm global_load_dwordx4 ("=&v": unsinkable, pinned, all in flight); (3) consume
// task tt behind s_waitcnt vmcnt(12-2tt) + sched_barrier(0) (rule #18 fence).
__global__ __launch_bounds__(256, 4) void k_gcnm(const float* __restrict__ x, const float* __restrict__ Asum,
                                                 const u16* __restrict__ gwb, const float* __restrict__ gb,
                                                 u16* __restrict__ xg){
  __shared__ __align__(16) u16 A_lds[128*64];   // 16 KB, XOR-swizzled granules
  __shared__ __align__(16) u16 B_lds[128*64];   // 16 KB, XOR-swizzled granules
  int bx = blockIdx.x;
  int n  = bx / MT;
  int m0 = (bx % MT) * 128;
  int t0 = m0 / VV, r0 = m0 % VV;
  int tid = threadIdx.x;
  int lane = tid & 63, wv = tid >> 6;
  int wm = (wv & 1) * 64, wo = (wv >> 1) * 64;
  int lr = lane & 15, lq = lane >> 4;

  // ---- stage B (gwb, 16 KB) via async16: LDS linear, global source pre-swizzled ----
  // LDS granule G=(row,g') holds global granule (row, g'^(row&7)) => read side unchanged.
  {
    const char* gB = (const char*)gwb;
    char* lB = (char*)B_lds;
    #pragma unroll
    for (int i = 0; i < 4; ++i){
      int G = i*256 + tid;
      int row = G >> 3, gp = G & 7;
      int src = (row*8 + (gp ^ (row & 7)))*16;
      async16(gB + src, lB + G*16);
    }
  }

  // ---- A_sum^T B-fragments in registers (compiler loads; before x-issue on purpose) ----
  s8v bfw[2];
  #pragma unroll
  for (int wt = 0; wt < 2; ++wt){
    u16 tmp[8];
    int w = lr + 16*wt;
    #pragma unroll
    for (int j = 0; j < 8; ++j){
      int v = lq*8 + j;
      tmp[j] = (w < VV && v < VV) ? f2b(Asum[v*VV + w]) : (u16)0;
    }
    bfw[wt] = *(s8v*)tmp;
  }

  // clean vmcnt slate: B-stage + Asum drained, so the counted waits below see only x-loads
  asm volatile("s_waitcnt vmcnt(0)" ::: "memory");
  __builtin_amdgcn_sched_barrier(0);

  // ---- issue all 14 x loads via inline asm (unsinkable, pinned, clamped addresses) ----
  const size_t XTOT = (size_t)NB*CC*TT*VV;   // 15,360,000 floats
  f4v xa7[7], xb7[7];
  #pragma unroll
  for (int tt = 0; tt < 7; ++tt){
    int tau = tt*4 + wv;
    int it = tau >> 2, ct = tau & 3;
    int t  = t0 + it;
    int c  = ct*16 + lr;
    size_t off = ((size_t)(n*CC + c)*TT + t)*VV + lq*8;
    if (lq == 3) off -= 7;               // lq==3: target v=24 lands at xb7[tt][3]
    if (off > XTOT - 8) off = XTOT - 8;  // clamp masked (t>=TT) tail reads only
    const float* xp = x + off;
    asm volatile("global_load_dwordx4 %0, %1, off"            : "=&v"(xa7[tt]) : "v"(xp));
    asm volatile("global_load_dwordx4 %0, %1, off offset:16"  : "=&v"(xb7[tt]) : "v"(xp));
  }

  // ---- consume: counted drain, convert + MFMA + swizzled LDS write ----
  #pragma unroll
  for (int tt = 0; tt < 7; ++tt){
    if      (tt == 0) asm volatile("s_waitcnt vmcnt(12)" ::: "memory");
    else if (tt == 1) asm volatile("s_waitcnt vmcnt(10)" ::: "memory");
    else if (tt == 2) asm volatile("s_waitcnt vmcnt(8)"  ::: "memory");
    else if (tt == 3) asm volatile("s_waitcnt vmcnt(6)"  ::: "memory");
    else if (tt == 4) asm volatile("s_waitcnt vmcnt(4)"  ::: "memory");
    else if (tt == 5) asm volatile("s_waitcnt vmcnt(2)"  ::: "memory");
    else              asm volatile("s_waitcnt vmcnt(0)"  ::: "memory");
    __builtin_amdgcn_sched_barrier(0);

    int tau = tt*4 + wv;
    int it = tau >> 2, ct = tau & 3;
    int t  = t0 + it;
    bool valid = (t < TT);
    u16 pk[8];
    if (lq < 3){
      if (valid){
        pk[0]=f2b(xa7[tt][0]); pk[1]=f2b(xa7[tt][1]); pk[2]=f2b(xa7[tt][2]); pk[3]=f2b(xa7[tt][3]);
        pk[4]=f2b(xb7[tt][0]); pk[5]=f2b(xb7[tt][1]); pk[6]=f2b(xb7[tt][2]); pk[7]=f2b(xb7[tt][3]);
      } else {
        #pragma unroll
        for (int j = 0; j < 8; ++j) pk[j] = 0;
      }
    } else {
      pk[0] = valid ? f2b(xb7[tt][3]) : (u16)0;   // v=24 lives at xb7[3] (off-7 shift)
      pk[1]=0; pk[2]=0; pk[3]=0; pk[4]=0; pk[5]=0; pk[6]=0; pk[7]=0;
    }
    s8v af = *(s8v*)pk;
    f4v d0 = (f4v)(0.f), d1 = (f4v)(0.f);
    d0 = __builtin_amdgcn_mfma_f32_16x16x32_bf16(af, bfw[0], d0, 0, 0, 0);
    d1 = __builtin_amdgcn_mfma_f32_16x16x32_bf16(af, bfw[1], d1, 0, 0, 0);
    int cb = ct*16 + lq*4;
    int g  = cb >> 3, co = cb & 7;
    int ml0 = it*VV + lr - r0;                    // w = lr
    if (ml0 >= 0 && ml0 < 128){
      u16 q[4];
      #pragma unroll
      for (int rg = 0; rg < 4; ++rg) q[rg] = f2b(d0[rg]);
      *(h4v*)&A_lds[ml0*64 + ((g ^ (ml0 & 7))*8) + co] = *(h4v*)q;
    }
    int w1 = lr + 16;
    int ml1 = it*VV + w1 - r0;
    if (w1 < VV && ml1 >= 0 && ml1 < 128){
      u16 q[4];
      #pragma unroll
      for (int rg = 0; rg < 4; ++rg) q[rg] = f2b(d1[rg]);
      *(h4v*)&A_lds[ml1*64 + ((g ^ (ml1 & 7))*8) + co] = *(h4v*)q;
    }
  }
  __syncthreads();

  // ---- main GEMM: 64m x 64o per wave, K=64 (2 substeps) ----
  f4v acc[4][4];
  #pragma unroll
  for (int mi = 0; mi < 4; ++mi)
    #pragma unroll
    for (int ni = 0; ni < 4; ++ni) acc[mi][ni] = (f4v)(0.f);
  #pragma unroll
  for (int ks = 0; ks < 2; ++ks){
    int p = ((ks*4 + lq) ^ (lane & 7)) * 8;
    s8v af[4], bf[4];
    #pragma unroll
    for (int mi = 0; mi < 4; ++mi)
      af[mi] = *(const s8v*)&A_lds[(wm + mi*16 + lr)*64 + p];
    #pragma unroll
    for (int ni = 0; ni < 4; ++ni)
      bf[ni] = *(const s8v*)&B_lds[(wo + ni*16 + lr)*64 + p];
    #pragma unroll
    for (int mi = 0; mi < 4; ++mi)
      #pragma unroll
      for (int ni = 0; ni < 4; ++ni)
        acc[mi][ni] = __builtin_amdgcn_mfma_f32_16x16x32_bf16(af[mi], bf[ni], acc[mi][ni], 0, 0, 0);
  }

  float bias[4];
  #pragma unroll
  for (int ni = 0; ni < 4; ++ni) bias[ni] = gb[wo + ni*16 + lr];
  #pragma unroll
  for (int mi = 0; mi < 4; ++mi){
    int mr = m0 + wm + mi*16 + lq*4;
    #pragma unroll
    for (int ni = 0; ni < 4; ++ni){
      int o = wo + ni*16 + lr;
      #pragma unroll
      for (int rg = 0; rg < 4; ++rg){
        int m = mr + rg;
        if (m < MM)
          xg[((size_t)n*MM + m)*OO + o] = f2b(acc[mi][ni][rg] + bias[ni]);
      }
    }
  }
}

// ---------------- tcn as MFMA implicit GEMM + fused BN partial stats ----------------
// v6 = R2 structure (measured 56.5 us, 0 bank conflicts) + chunked XCD swizzle.
// K-step 64 (18 steps), 512 threads (8 waves: 4 m-strips x 2 o-halves), LDS 2x16+2x16 KB,
// counted vmcnt(4) 1-deep prefetch. K-64 keeps each 128 B xg line within ONE step
// (K-32 split lines across steps -> +52 MB FETCH, R4/R5 lesson).
__global__ __launch_bounds__(512, 4) void k_tcnm(const u16* __restrict__ xg, const u16* __restrict__ Wq2,
                                                 const float* __restrict__ tb, const u16* __restrict__ zbuf,
                                                 u16* __restrict__ xt, float* __restrict__ psum,
                                                 float* __restrict__ psq){
  __shared__ __align__(16) u16 A_lds[2][128*64];   // 2 x 16 KB
  __shared__ __align__(16) u16 B_lds[2][128*64];   // 2 x 16 KB
  __shared__ float sredS[8][64];
  __shared__ float sredQ[8][64];
  int bx = blockIdx.x;
  int lg = ((bx & 7) * 120) + (bx >> 3);   // bijective: 960 = 8 * 120; XCD owns 4 n's
  int n  = lg / 30;
  int m0 = (lg % 30) * 128;
  int tid = threadIdx.x;
  int lane = tid & 63, wv = tid >> 6;
  int wm = (wv >> 1) * 32, wo = (wv & 1) * 64;   // 8 waves: 4 m-strips x 2 o-halves
  int lr = lane & 15, lq = lane >> 4;

  int rlow = tid >> 3;                 // 0..63: row within 64-row half-tile
  int gsrc = (tid & 7) ^ (rlow & 7);
  int tid16 = tid * 16;
  int  tbse[2], vr[2]; bool vm[2];
  #pragma unroll
  for (int it = 0; it < 2; ++it){
    int m = m0 + it*64 + rlow;
    vm[it] = (m < M2);
    int t2 = m / VV, v = m - t2*VV;
    tbse[it] = 2*t2 - 4;
    vr[it] = v;
  }
  size_t basen = (size_t)n*MM*OO + (size_t)gsrc*8;

  f4v acc[2][4];
  #pragma unroll
  for (int mi = 0; mi < 2; ++mi)
    #pragma unroll
    for (int ni = 0; ni < 4; ++ni) acc[mi][ni] = (f4v)(0.f);

  // 4 global_load_lds per thread per K-step (2 A halves + 2 B halves)
  auto stage = [&](int kc, int b){
    int k  = kc >> 1;
    int i0 = (kc & 1) * 64;
    const u16* wbase = Wq2 + kc*8192;
    char* Ab = (char*)(&A_lds[b][0]);
    char* Bb = (char*)(&B_lds[b][0]);
    #pragma unroll
    for (int it = 0; it < 2; ++it){
      int t = tbse[it] + k;
      const u16* ga = (vm[it] && t >= 0 && t < TT)
                      ? xg + basen + (size_t)(t*VV + vr[it])*OO + i0
                      : zbuf;
      async16(ga, Ab + it*8192 + tid16);
      async16(wbase + ((it*64 + rlow)*64 + gsrc*8), Bb + it*8192 + tid16);
    }
  };

  stage(0, 0);                         // prologue: tile 0 in flight (4 loads/thread)
  for (int kc = 0; kc < 18; ++kc){
    int cur = kc & 1;
    if (kc < 17){
      stage(kc + 1, cur ^ 1);          // 8 outstanding per thread
      asm volatile("s_waitcnt vmcnt(4)" ::: "memory");   // cur's 4 landed; next 4 in flight
    } else {
      asm volatile("s_waitcnt vmcnt(0)" ::: "memory");   // last tile: drain
    }
    __builtin_amdgcn_s_barrier();      // all waves' cur-tile loads visible
    asm volatile("" ::: "memory");     // fence: keep ds_reads below the barrier

    const u16* Ac = &A_lds[cur][0];
    const u16* Bc = &B_lds[cur][0];
    #pragma unroll
    for (int ks = 0; ks < 2; ++ks){
      int p = ((ks*4 + lq) ^ (lane & 7)) * 8;
      s8v af[2], bf[4];
      #pragma unroll
      for (int mi = 0; mi < 2; ++mi)
        af[mi] = *(const s8v*)&Ac[(wm + mi*16 + lr)*64 + p];
      #pragma unroll
      for (int ni = 0; ni < 4; ++ni)
        bf[ni] = *(const s8v*)&Bc[(wo + ni*16 + lr)*64 + p];
      #pragma unroll
      for (int mi = 0; mi < 2; ++mi)
        #pragma unroll
        for (int ni = 0; ni < 4; ++ni)
          acc[mi][ni] = __builtin_amdgcn_mfma_f32_16x16x32_bf16(af[mi], bf[ni], acc[mi][ni], 0, 0, 0);
    }
    asm volatile("s_waitcnt lgkmcnt(0)" ::: "memory");   // reads complete before crossing
    __builtin_amdgcn_s_barrier();      // all waves done reading cur -> safe to overwrite
    asm volatile("" ::: "memory");
  }

  float bias[4];
  #pragma unroll
  for (int ni = 0; ni < 4; ++ni) bias[ni] = tb[wo + ni*16 + lr];
  float sni[4] = {0.f,0.f,0.f,0.f}, qni[4] = {0.f,0.f,0.f,0.f};
  #pragma unroll
  for (int mi = 0; mi < 2; ++mi){
    int mr = m0 + wm + mi*16 + lq*4;
    #pragma unroll
    for (int ni = 0; ni < 4; ++ni){
      int o = wo + ni*16 + lr;
      #pragma unroll
      for (int rg = 0; rg < 4; ++rg){
        int mm = mr + rg;
        if (mm < M2){
          float val = acc[mi][ni][rg] + bias[ni];
          xt[((size_t)n*M2 + mm)*OO + o] = f2b(val);
          sni[ni] += val;
          qni[ni] += val*val;
        }
      }
    }
  }
  // cross-lq reduce (lanes differ by 16/32), then cross-wave combine via LDS
  #pragma unroll
  for (int ni = 0; ni < 4; ++ni){
    float s = sni[ni], q = qni[ni];
    s += __shfl_xor(s, 16); s += __shfl_xor(s, 32);
    q += __shfl_xor(q, 16); q += __shfl_xor(q, 32);
    if (lane < 16){
      sredS[wv][ni*16 + lane] = s;
      sredQ[wv][ni*16 + lane] = q;
    }
  }
  __syncthreads();
  // waves with (wv&1) == (o>>6) cover output column o; 4 such waves each
  if (tid < 128){
    int o = tid, h = o >> 6, lo = o & 63;
    psum[(size_t)lg*128 + o] = (sredS[h][lo] + sredS[h+2][lo]) + (sredS[h+4][lo] + sredS[h+6][lo]);
  } else if (tid < 256){
    int o = tid - 128, h = o >> 6, lo = o & 63;
    psq [(size_t)lg*128 + o] = (sredQ[h][lo] + sredQ[h+2][lo]) + (sredQ[h+4][lo] + sredQ[h+6][lo]);
  }
}

// ---------------- BN stats finalize, stage a: 60 blocks reduce 16 partial rows each ----------------
__global__ __launch_bounds__(256) void k_stats2a(const float* __restrict__ psum, const float* __restrict__ psq,
                                                 float* __restrict__ ps2, float* __restrict__ pq2){
  __shared__ float bufS[256], bufQ[256];
  int tid = threadIdx.x, b = blockIdx.x;
  int o = tid & 127, h = tid >> 7;
  float s = 0.f, q = 0.f;
  for (int r = b*16 + h; r < b*16 + 16; r += 2){
    s += psum[(size_t)r*128 + o];
    q += psq [(size_t)r*128 + o];
  }
  bufS[tid] = s; bufQ[tid] = q;
  __syncthreads();
  if (tid < 128){
    ps2[(size_t)b*128 + o] = bufS[tid] + bufS[tid + 128];
    pq2[(size_t)b*128 + o] = bufQ[tid] + bufQ[tid + 128];
  }
}

// ---------------- BN stats finalize, stage b: reduce 60 level-2 rows ----------------
__global__ __launch_bounds__(256) void k_stats2b(const float* __restrict__ ps2, const float* __restrict__ pq2,
                                                 const float* __restrict__ gamma, const float* __restrict__ beta,
                                                 float* __restrict__ stats){
  __shared__ float bufS[256], bufQ[256];
  int tid = threadIdx.x;
  int o = tid & 127, h = tid >> 7;
  float s = 0.f, q = 0.f;
  for (int b = h; b < 60; b += 2){
    s += ps2[(size_t)b*128 + o];
    q += pq2[(size_t)b*128 + o];
  }
  bufS[tid] = s; bufQ[tid] = q;
  __syncthreads();
  if (tid < 128){
    s = bufS[tid] + bufS[tid + 128];
    q = bufQ[tid] + bufQ[tid + 128];
    const float inv = 1.f / 120000.f;
    float mean = s * inv;
    float var  = q * inv - mean*mean;
    float sc = gamma[o] * rsqrtf(var + 1e-5f);
    stats[o]       = sc;
    stats[128 + o] = beta[o] - mean * sc;
  }
}

// ---------------- res as MFMA implicit GEMM + BN + relu: M=(t2*25+v), N=128 o, K=64 c ----------------
// out[n][o][m] with m = t2*25+v  (== reference (N,O,T2,V))
// v4: coalesced output via LDS transpose (store loop covers all 64 rows: 16 iter x 4 rows).
__global__ __launch_bounds__(256, 4) void k_resm(const float* __restrict__ x, const u16* __restrict__ rwb,
                                                 const float* __restrict__ rb, const u16* __restrict__ xt,
                                                 const float* __restrict__ stats, float* __restrict__ out){
  __shared__ __align__(16) char smem[64*130*4];   // 33280 B: staging (32 KB) then transpose buf
  u16* A_lds = (u16*)smem;                        // [128*64]
  u16* B_lds = A_lds + 128*64;                    // [128*64]
  float* tbuf = (float*)smem;                     // [64][130] f32, aliases A/B after GEMM
  int bx = blockIdx.x;
  int n  = bx / 30;
  int m0 = (bx % 30) * 128;
  int t20 = m0 / VV, r0 = m0 % VV;
  int tid = threadIdx.x;
  int lane = tid & 63, wv = tid >> 6;
  int wm = (wv & 1) * 64, wo = (wv >> 1) * 64;
  int lr = lane & 15, lq = lane >> 4;

  {
    const u32* g32 = (const u32*)rwb;
    u32* b32 = (u32*)B_lds;
    for (int s = tid; s < 4096; s += 256){
      int row = s >> 5, col = s & 31;
      int g = col >> 2, c2 = col & 3;
      b32[row*32 + ((g ^ (row & 7))*4 + c2)] = g32[s];
    }
  }

  // stage A: tasks (cg, t2i, v): 8 c's packed into one ds_write_b128
  for (int task = tid; task < 8*7*VV; task += 256){
    int cg  = task / (7*VV);
    int rem = task - cg*(7*VV);
    int t2i = rem / VV, v = rem - t2i*VV;
    int t2 = t20 + t2i;
    int ml = t2i*VV + v - r0;
    if (ml >= 0 && ml < 128){
      u16 pk[8];
      if (t2 < TO){
        const float* xp = x + ((size_t)(n*CC + cg*8)*TT + 2*t2)*VV + v;
        #pragma unroll
        for (int cc = 0; cc < 8; ++cc) pk[cc] = f2b(xp[(size_t)cc*(TT*VV)]);
      } else {
        #pragma unroll
        for (int cc = 0; cc < 8; ++cc) pk[cc] = 0;
      }
      *(h8v*)&A_lds[ml*64 + ((cg ^ (ml & 7))*8)] = *(h8v*)pk;
    }
  }
  __syncthreads();

  f4v acc[4][4];
  #pragma unroll
  for (int mi = 0; mi < 4; ++mi)
    #pragma unroll
    for (int ni = 0; ni < 4; ++ni) acc[mi][ni] = (f4v)(0.f);
  #pragma unroll
  for (int ks = 0; ks < 2; ++ks){
    int p = ((ks*4 + lq) ^ (lane & 7)) * 8;
    s8v af[4], bf[4];
    #pragma unroll
    for (int mi = 0; mi < 4; ++mi)
      af[mi] = *(const s8v*)&A_lds[(wm + mi*16 + lr)*64 + p];
    #pragma unroll
    for (int ni = 0; ni < 4; ++ni)
      bf[ni] = *(const s8v*)&B_lds[(wo + ni*16 + lr)*64 + p];
    #pragma unroll
    for (int mi = 0; mi < 4; ++mi)
      #pragma unroll
      for (int ni = 0; ni < 4; ++ni)
        acc[mi][ni] = __builtin_amdgcn_mfma_f32_16x16x32_bf16(af[mi], bf[ni], acc[mi][ni], 0, 0, 0);
  }

  float sc[4], sb[4], rr[4];
  #pragma unroll
  for (int ni = 0; ni < 4; ++ni){
    int o = wo + ni*16 + lr;
    sc[ni] = stats[o]; sb[ni] = stats[128 + o]; rr[ni] = rb[o];
  }

  // ---- pass p: waves with wo==64p compute+deposit their o-half into tbuf; all store ----
  #pragma unroll
  for (int pass = 0; pass < 2; ++pass){
    __syncthreads();   // pass0: GEMM ds_reads done (smem reuse); pass1: prev stores done
    if ((wv >> 1) == pass){
      #pragma unroll
      for (int mi = 0; mi < 4; ++mi){
        int mb   = m0 + wm + mi*16 + lq*4;
        int mloc = wm + mi*16 + lq*4;
        #pragma unroll
        for (int ni = 0; ni < 4; ++ni){
          int o    = wo + ni*16 + lr;
          int oloc = ni*16 + lr;
          size_t xb = ((size_t)n*M2 + mb)*OO + o;
          float v2[4];
          #pragma unroll
          for (int rg = 0; rg < 4; ++rg){
            float val = 0.f;
            if (mb + rg < M2)
              val = fmaxf(sc[ni]*b2f(xt[xb + (size_t)rg*OO]) + sb[ni] + acc[mi][ni][rg] + rr[ni], 0.f);
            v2[rg] = val;
          }
          *(float2*)&tbuf[oloc*130 + mloc]     = make_float2(v2[0], v2[1]);
          *(float2*)&tbuf[oloc*130 + mloc + 2] = make_float2(v2[2], v2[3]);
        }
      }
    }
    __syncthreads();
    // cooperative coalesced store: 64 rows x 128 f32, float2 per lane, 4 rows/iter x 16
    #pragma unroll
    for (int it = 0; it < 16; ++it){
      int row = it*4 + (tid >> 6);        // 4 rows/iter, 64 lanes/row
      int c2  = (tid & 63) * 2;
      int o   = pass*64 + row;
      int mg  = m0 + c2;
      size_t ob = ((size_t)(n*OO + o))*M2 + mg;
      float2 vv = *(float2*)&tbuf[row*130 + c2];
      if (mg + 1 < M2)      *(float2*)&out[ob] = vv;
      else if (mg < M2)     out[ob] = vv.x;
    }
  }
}

extern "C" void kernel_launch(void* const* d_in, const int* in_sizes, int n_in,
                              void* d_out, int out_size, void* d_ws, size_t ws_size,
                              hipStream_t stream) {
  const float* x     = (const float*)d_in[0];
  const float* Ap    = (const float*)d_in[1];
  const float* ei    = (const float*)d_in[2];
  const float* gw    = (const float*)d_in[3];
  const float* gb    = (const float*)d_in[4];
  const float* tw    = (const float*)d_in[5];
  const float* tb    = (const float*)d_in[6];
  const float* gamma = (const float*)d_in[7];
  const float* beta  = (const float*)d_in[8];
  const float* rw    = (const float*)d_in[9];
  const float* rb    = (const float*)d_in[10];
  float* out = (float*)d_out;

  char* ws = (char*)d_ws;
  float* Asum  = (float*)ws;                      // 2500 B
  float* zbuf  = (float*)(ws + 2560);             // 512 B zero page
  u16*   Wq2   = (u16*)(ws + 4096);               // 294912 B -> 299008
  u16*   gwb   = (u16*)(ws + 299008);             // 16384 B  -> 315392
  u16*   rwb   = (u16*)(ws + 315392);             // 16384 B  -> 331776
  float* stats = (float*)(ws + 331776);           // 1024 B   -> 332800
  float* psum  = (float*)(ws + 333824);           // 491520 B -> 825344
  float* psq   = (float*)(ws + 825344);           // 491520 B -> 1316864
  float* ps2   = (float*)(ws + 1316864);          // 30720 B  -> 1347584
  float* pq2   = (float*)(ws + 1347584);          // 30720 B  -> 1378304
  u16*   xg    = (u16*)(ws + (2u<<20));           // 61,440,000 B [n][m=t*25+v][o] bf16
  u16*   xt    = (u16*)(ws + 63537152);           // 28,800,000 B [n][m=t2*25+v][o] bf16 (~92.3 MB total)

  k_prep   <<<dim3(644),    dim3(256), 0, stream>>>(Ap, ei, tw, gw, rw, Asum, zbuf, Wq2, gwb, rwb);
  k_gcnm   <<<dim3(NB*MT),  dim3(256), 0, stream>>>(x, Asum, gwb, gb, xg);
  k_tcnm   <<<dim3(NB*30),  dim3(512), 0, stream>>>(xg, Wq2, tb, (const u16*)zbuf, xt, psum, psq);
  k_stats2a<<<dim3(60),     dim3(256), 0, stream>>>(psum, psq, ps2, pq2);
  k_stats2b<<<dim3(1),      dim3(256), 0, stream>>>(ps2, pq2, gamma, beta, stats);
  k_resm   <<<dim3(NB*30),  dim3(256), 0, stream>>>(x, rwb, rb, xt, stats, out);
}